// Round 14
// baseline (470.642 us; speedup 1.0000x reference)
//
#include <hip/hip_runtime.h>
#include <hip/hip_bf16.h>
#include <math.h>

// ---------------------------------------------------------------------------
// 3-layer GAT forward. Round 14: non-GEMM fusion round.
//  - compute_al for layers 2/3 fused into GEMM 1/2 epilogues (16-lane shfl
//    reduce + atomicAdd into als/ald). Removes two 40MB-read kernels.
//  - sum-of-squares fused into GEMM 3 epilogue -> one-pass normalize.
//  - edge_index read directly as int32 (R1==R2 proved int32 path).
//  - all atomic accumulators zeroed by one hipMemsetAsync per call.
// GEMM K-loop identical to R13 (128x128, 2 buf, vmcnt(4), (256,4)).
// ---------------------------------------------------------------------------

typedef __attribute__((ext_vector_type(8))) short short8;
typedef __attribute__((ext_vector_type(4))) float f32x4;

#define GLOAD_LDS16(g, l)                                            \
  __builtin_amdgcn_global_load_lds(                                  \
      (const __attribute__((address_space(1))) void*)(g),            \
      (__attribute__((address_space(3))) void*)(l), 16, 0, 0)

#define CFENCE asm volatile("" ::: "memory")

__device__ __forceinline__ float bf16_to_f32(ushort u) {
  return __uint_as_float(((unsigned int)u) << 16);
}

__device__ __forceinline__ float block_reduce_sum_bcast(float v) {
#pragma unroll
  for (int off = 32; off > 0; off >>= 1) v += __shfl_down(v, off, 64);
  __shared__ float tmp[4];
  __shared__ float res;
  int lane = threadIdx.x & 63, w = threadIdx.x >> 6;
  if (lane == 0) tmp[w] = v;
  __syncthreads();
  if (threadIdx.x == 0) res = tmp[0] + tmp[1] + tmp[2] + tmp[3];
  __syncthreads();
  float out = res;
  __syncthreads();
  return out;
}

__device__ __forceinline__ float block_reduce_max_bcast(float v) {
#pragma unroll
  for (int off = 32; off > 0; off >>= 1) v = fmaxf(v, __shfl_down(v, off, 64));
  __shared__ float tmpm[4];
  __shared__ float resm;
  int lane = threadIdx.x & 63, w = threadIdx.x >> 6;
  if (lane == 0) tmpm[w] = v;
  __syncthreads();
  if (threadIdx.x == 0) resm = fmaxf(fmaxf(tmpm[0], tmpm[1]), fmaxf(tmpm[2], tmpm[3]));
  __syncthreads();
  float out = resm;
  __syncthreads();
  return out;
}

// ---------------------------------------------------------------------------
__global__ __launch_bounds__(256) void convert_f32_bf16(const float* __restrict__ in,
                                                        __hip_bfloat16* __restrict__ out,
                                                        int n) {
  int i = blockIdx.x * blockDim.x + threadIdx.x;
  if (i < n) out[i] = __float2bfloat16(in[i]);
}

// ---------------------------------------------------------------------------
// Transpose W [K][N] f32 -> Wt [N][K] bf16.  32x32 tiles, 256 threads.
// ---------------------------------------------------------------------------
__global__ __launch_bounds__(256) void transpose_w(const float* __restrict__ W,
                                                   __hip_bfloat16* __restrict__ Wt,
                                                   int K, int Nout) {
  __shared__ float t[32][33];
  int tx = threadIdx.x & 31, ty = threadIdx.x >> 5;  // 32 x 8
  int n0 = blockIdx.x * 32, k0 = blockIdx.y * 32;
#pragma unroll
  for (int i = 0; i < 4; ++i) {
    int k = k0 + ty + i * 8;
    t[ty + i * 8][tx] = W[(size_t)k * Nout + n0 + tx];
  }
  __syncthreads();
#pragma unroll
  for (int i = 0; i < 4; ++i) {
    int n = n0 + ty + i * 8;
    Wt[(size_t)n * K + k0 + tx] = __float2bfloat16(t[tx][ty + i * 8]);
  }
}

// ---------------------------------------------------------------------------
// wa_s[k] = sum_f W[k][f] * a_s[f];  wa_d likewise.  W row-major [K][F] f32.
// ---------------------------------------------------------------------------
__global__ __launch_bounds__(256) void matvec_wa(const float* __restrict__ W,
                                                 const float* __restrict__ a_s,
                                                 const float* __restrict__ a_d,
                                                 float* __restrict__ wa_s,
                                                 float* __restrict__ wa_d, int F) {
  int k = blockIdx.x;
  const float* row = W + (size_t)k * F;
  float s1 = 0.f, s2 = 0.f;
  for (int f = threadIdx.x; f < F; f += 256) {
    float w = row[f];
    s1 += w * a_s[f];
    s2 += w * a_d[f];
  }
  float r1 = block_reduce_sum_bcast(s1);
  float r2 = block_reduce_sum_bcast(s2);
  if (threadIdx.x == 0) {
    wa_s[k] = r1;
    wa_d[k] = r2;
  }
}

// ---------------------------------------------------------------------------
// als[n] = dot(H[n,:], wa_s) for layer 1 (F=256, bf16 H).
// ---------------------------------------------------------------------------
__global__ __launch_bounds__(256) void compute_al1(const ushort* __restrict__ H,
                                                   const float* __restrict__ wa_s,
                                                   const float* __restrict__ wa_d,
                                                   float* __restrict__ als,
                                                   float* __restrict__ ald) {
  int n = blockIdx.x;
  const ushort* row = H + (size_t)n * 256;
  float f = bf16_to_f32(row[threadIdx.x]);
  float s1 = f * wa_s[threadIdx.x];
  float s2 = f * wa_d[threadIdx.x];
  float r1 = block_reduce_sum_bcast(s1);
  float r2 = block_reduce_sum_bcast(s2);
  if (threadIdx.x == 0) {
    als[n] = r1;
    ald[n] = r2;
  }
}

// ---------------------------------------------------------------------------
// CSR build (edge_index is int32: [2][E], src then dst)
// ---------------------------------------------------------------------------
__global__ void count_kernel(const int* __restrict__ dst, int* __restrict__ counts, int E) {
  int i = blockIdx.x * blockDim.x + threadIdx.x;
  if (i < E) atomicAdd(&counts[dst[i]], 1);
}

__global__ __launch_bounds__(1024) void scan_kernel(const int* __restrict__ counts,
                                                    int* __restrict__ rowptr,
                                                    int* __restrict__ cursor, int Nn) {
  __shared__ int part[1024];
  int tid = threadIdx.x;
  int chunk = (Nn + 1023) / 1024;
  int base = tid * chunk;
  int s = 0;
  for (int i = 0; i < chunk; ++i) {
    int idx = base + i;
    if (idx < Nn) s += counts[idx];
  }
  part[tid] = s;
  __syncthreads();
  for (int off = 1; off < 1024; off <<= 1) {
    int v = 0;
    if (tid >= off) v = part[tid - off];
    __syncthreads();
    if (tid >= off) part[tid] += v;
    __syncthreads();
  }
  int run = (tid == 0) ? 0 : part[tid - 1];
  for (int i = 0; i < chunk; ++i) {
    int idx = base + i;
    if (idx < Nn) {
      rowptr[idx] = run;
      cursor[idx] = run;
      run += counts[idx];
    }
  }
  if (tid == 1023) rowptr[Nn] = part[1023];
}

__global__ void fill_kernel(const int* __restrict__ src, const int* __restrict__ dst,
                            int* __restrict__ cursor, int* __restrict__ eidx, int E) {
  int i = blockIdx.x * blockDim.x + threadIdx.x;
  if (i < E) {
    int pos = atomicAdd(&cursor[dst[i]], 1);
    eidx[pos] = src[i];
  }
}

// ---------------------------------------------------------------------------
// H_agg[n] = sum_e alpha_e * H_in[src_e]  (softmax attention, self-loop incl).
// ---------------------------------------------------------------------------
template <int FPT>
__global__ __launch_bounds__(256) void aggregate(const ushort* __restrict__ H,
                                                 const float* __restrict__ als,
                                                 const float* __restrict__ ald,
                                                 const int* __restrict__ rowptr,
                                                 const int* __restrict__ eidx,
                                                 ushort* __restrict__ out, int F) {
  int n = blockIdx.x;
  int tid = threadIdx.x;
  int beg = rowptr[n], end = rowptr[n + 1];
  int deg = end - beg;
  float aldn = ald[n];

  float lm = -INFINITY;
  for (int j = tid; j < deg; j += 256) {
    int s = eidx[beg + j];
    float e = als[s] + aldn;
    e = (e > 0.f) ? e : 0.2f * e;
    lm = fmaxf(lm, e);
  }
  if (tid == 0) {
    float e = als[n] + aldn;
    e = (e > 0.f) ? e : 0.2f * e;
    lm = fmaxf(lm, e);
  }
  float m = block_reduce_max_bcast(lm);

  float ls = 0.f;
  for (int j = tid; j < deg; j += 256) {
    int s = eidx[beg + j];
    float e = als[s] + aldn;
    e = (e > 0.f) ? e : 0.2f * e;
    ls += expf(e - m);
  }
  if (tid == 0) {
    float e = als[n] + aldn;
    e = (e > 0.f) ? e : 0.2f * e;
    ls += expf(e - m);
  }
  float denom = block_reduce_sum_bcast(ls) + 1e-16f;
  float inv_denom = 1.f / denom;

  float acc[FPT];
#pragma unroll
  for (int i = 0; i < FPT; ++i) acc[i] = 0.f;

  __shared__ float alpha_sh[256];
  __shared__ int src_sh[256];
  int total = deg + 1;
  for (int c0 = 0; c0 < total; c0 += 256) {
    int j = c0 + tid;
    if (j < total) {
      int s = (j < deg) ? eidx[beg + j] : n;
      float e = als[s] + aldn;
      e = (e > 0.f) ? e : 0.2f * e;
      alpha_sh[tid] = expf(e - m) * inv_denom;
      src_sh[tid] = s;
    }
    __syncthreads();
    int cn = min(256, total - c0);
    for (int jj = 0; jj < cn; ++jj) {
      float al = alpha_sh[jj];
      const ushort* row = H + (size_t)src_sh[jj] * F;
      if (FPT == 1) {
        acc[0] += al * bf16_to_f32(row[tid]);
      } else {
#pragma unroll
        for (int i = 0; i < FPT / 2; ++i) {
          unsigned int u = *(const unsigned int*)(row + tid * 2 + i * 512);
          acc[2 * i]     += al * __uint_as_float((u & 0xffffu) << 16);
          acc[2 * i + 1] += al * __uint_as_float(u & 0xffff0000u);
        }
      }
    }
    __syncthreads();
  }

#pragma unroll
  for (int i = 0; i < FPT; ++i) {
    int col = (FPT == 1) ? tid : (tid * 2 + (i >> 1) * 512 + (i & 1));
    __hip_bfloat16 hv = __float2bfloat16(acc[i]);
    out[(size_t)n * F + col] = *(ushort*)&hv;
  }
}

// ---------------------------------------------------------------------------
// C = ReLU(A @ Bt^T + bias).  A [M][K] bf16, Bt [Nout][K] bf16.
// BM=128, BN=128, BK=32, 256 threads (4 waves 2Mx2N), (256,4) reg budget.
// 2 LDS buffers (32 KiB), prefetch distance 1, vmcnt(4).
// EPI=1: fused next-layer attention logits — per-row partial dot with
//   wa_s/wa_d, 16-lane shfl reduce, atomicAdd to aux1/aux2 (pre-zeroed).
// EPI=2: fused sum-of-squares per row -> atomicAdd aux1 (for normalize).
// ---------------------------------------------------------------------------
template <bool BF16OUT, int EPI>
__global__ __launch_bounds__(256, 4) void gemm_t128(const ushort* __restrict__ A,
                                                    const ushort* __restrict__ Bt,
                                                    const float* __restrict__ bias,
                                                    void* __restrict__ C,
                                                    const float* __restrict__ wa_s,
                                                    const float* __restrict__ wa_d,
                                                    float* __restrict__ aux1,
                                                    float* __restrict__ aux2,
                                                    int M, int K, int Nout) {
  constexpr int BUF = 8192;  // ushorts per buffer (A 128x32 + B 128x32)
  extern __shared__ ushort lds[];
  const int tid = threadIdx.x;
  const int l = tid & 63, w = tid >> 6;
  const int wm = w >> 1, wn = w & 1;
  const int l15 = l & 15, lhi = l >> 4;

  // bijective XCD-chunked block swizzle (nwg % 8 == 0 for all our grids)
  int nwg = gridDim.x * gridDim.y;
  int lin = blockIdx.y * gridDim.x + blockIdx.x;
  if ((nwg & 7) == 0) lin = (lin & 7) * (nwg >> 3) + (lin >> 3);
  const int bx = lin % gridDim.x, by = lin / gridDim.x;
  const int row0 = by * 128, col0 = bx * 128;

  const int c8sw = (l & 3) ^ (((l >> 5) & 1) << 1);
  const int lrow = l >> 2;
  const int chsw = lhi ^ (((l15 >> 3) & 1) << 1);
  const int rd_off = l15 * 32 + chsw * 8;

  const int sA0 = w * 2;
  const ushort* ga[2];
  const ushort* gb[2];
#pragma unroll
  for (int j = 0; j < 2; ++j) {
    int ar = min(row0 + (sA0 + j) * 16 + lrow, M - 1);  // clamp; masked at C-write
    ga[j] = A + (size_t)ar * K + c8sw * 8;
    gb[j] = Bt + (size_t)(col0 + (sA0 + j) * 16 + lrow) * K + c8sw * 8;
  }

#define STAGE(nb, kn)                                                     \
  do {                                                                    \
    GLOAD_LDS16(ga[0] + (kn), &lds[(nb)*BUF + (sA0 + 0) * 512]);          \
    GLOAD_LDS16(ga[1] + (kn), &lds[(nb)*BUF + (sA0 + 1) * 512]);          \
    GLOAD_LDS16(gb[0] + (kn), &lds[(nb)*BUF + 4096 + (sA0 + 0) * 512]);   \
    GLOAD_LDS16(gb[1] + (kn), &lds[(nb)*BUF + 4096 + (sA0 + 1) * 512]);   \
  } while (0)

  f32x4 acc[4][4] = {};

#define PHASE(cur, WAITLIT, STAGE_STMT)                                              \
  do {                                                                               \
    STAGE_STMT;                                                                      \
    asm volatile("s_waitcnt vmcnt(" WAITLIT ")" ::: "memory");                       \
    __builtin_amdgcn_s_barrier();                                                    \
    CFENCE;                                                                          \
    short8 af[4], bf[4];                                                             \
    const ushort* Ab = &lds[(cur)*BUF];                                              \
    const ushort* Bb = &lds[(cur)*BUF + 4096];                                       \
    _Pragma("unroll") for (int m = 0; m < 4; ++m)                                    \
        af[m] = *(const short8*)(Ab + (wm * 4 + m) * 512 + rd_off);                  \
    _Pragma("unroll") for (int n = 0; n < 4; ++n)                                    \
        bf[n] = *(const short8*)(Bb + (wn * 4 + n) * 512 + rd_off);                  \
    __builtin_amdgcn_s_setprio(1);                                                   \
    _Pragma("unroll") for (int m = 0; m < 4; ++m)                                    \
        _Pragma("unroll") for (int n = 0; n < 4; ++n)                                \
            acc[m][n] = __builtin_amdgcn_mfma_f32_16x16x32_bf16(                     \
                af[m], bf[n], acc[m][n], 0, 0, 0);                                   \
    __builtin_amdgcn_s_setprio(0);                                                   \
    CFENCE;                                                                          \
    __builtin_amdgcn_s_barrier();                                                    \
    CFENCE;                                                                          \
  } while (0)

  const int nt = K >> 5;  // K/32; >= 8 for all layers here
  STAGE(0, 0);

  int cur = 0;
  for (int t = 0; t < nt - 1; ++t) {
    const int kn = (t + 1) << 5;
    PHASE(cur, "4", STAGE(cur ^ 1, kn));
    cur ^= 1;
  }
  PHASE(cur, "0", );

  // epilogue: D mapping col=lane&15, row=(lane>>4)*4+reg; fused bias+ReLU
  // + optional fused al-dot (EPI=1) / sum-of-squares (EPI=2).
#pragma unroll
  for (int mi = 0; mi < 4; ++mi) {
#pragma unroll
    for (int v = 0; v < 4; ++v) {
      int r = row0 + wm * 64 + mi * 16 + lhi * 4 + v;
      bool rin = (r < M);  // uniform across the 16-lane l15 group
      float pS = 0.f, pD = 0.f;
#pragma unroll
      for (int n = 0; n < 4; ++n) {
        int col = col0 + wn * 64 + n * 16 + l15;
        float val = fmaxf(acc[mi][n][v] + bias[col], 0.f);
        if (rin) {
          size_t idx = (size_t)r * Nout + col;
          if (BF16OUT)
            ((__hip_bfloat16*)C)[idx] = __float2bfloat16(val);
          else
            ((float*)C)[idx] = val;
          if (EPI == 1) {
            pS += val * wa_s[col];
            pD += val * wa_d[col];
          } else if (EPI == 2) {
            pS += val * val;
          }
        }
      }
      if (EPI == 1) {
#pragma unroll
        for (int off = 1; off < 16; off <<= 1) {
          pS += __shfl_xor(pS, off, 64);
          pD += __shfl_xor(pD, off, 64);
        }
        if (l15 == 0 && rin) {
          atomicAdd(&aux1[r], pS);
          atomicAdd(&aux2[r], pD);
        }
      } else if (EPI == 2) {
#pragma unroll
        for (int off = 1; off < 16; off <<= 1) pS += __shfl_xor(pS, off, 64);
        if (l15 == 0 && rin) atomicAdd(&aux1[r], pS);
      }
    }
  }
#undef PHASE
#undef STAGE
}

// ---------------------------------------------------------------------------
// Row L2 normalize using precomputed sum-of-squares (eps 1e-12).
// ---------------------------------------------------------------------------
__global__ __launch_bounds__(256) void normalize_ss(const float* __restrict__ h,
                                                    const float* __restrict__ ss,
                                                    float* __restrict__ out, int F) {
  int n = blockIdx.x;
  float inv = 1.f / fmaxf(sqrtf(ss[n]), 1e-12f);
  const float* row = h + (size_t)n * F;
  for (int f = threadIdx.x; f < F; f += 256) {
    out[(size_t)n * F + f] = row[f] * inv;
  }
}

// ---------------------------------------------------------------------------
extern "C" void kernel_launch(void* const* d_in, const int* in_sizes, int n_in,
                              void* d_out, int out_size, void* d_ws, size_t ws_size,
                              hipStream_t stream) {
  const float* x   = (const float*)d_in[0];
  const int*   ei  = (const int*)d_in[1];
  const float* W1  = (const float*)d_in[2];
  const float* W2  = (const float*)d_in[3];
  const float* W3  = (const float*)d_in[4];
  const float* a1s = (const float*)d_in[5];
  const float* a1d = (const float*)d_in[6];
  const float* a2s = (const float*)d_in[7];
  const float* a2d = (const float*)d_in[8];
  const float* a3s = (const float*)d_in[9];
  const float* a3d = (const float*)d_in[10];
  const float* b1  = (const float*)d_in[11];
  const float* b2  = (const float*)d_in[12];
  const float* b3  = (const float*)d_in[13];

  const int N = in_sizes[0] / 256;  // 10000
  const int E = in_sizes[1] / 2;    // 80000

  char* ws = (char*)d_ws;
  size_t off = 0;
  auto alloc = [&](size_t bytes) -> void* {
    void* p = ws + off;
    off += (bytes + 255) & ~(size_t)255;
    return p;
  };
  ushort* h    = (ushort*)alloc((size_t)N * 2048 * 2);  // activations bf16
  ushort* hagg = (ushort*)alloc((size_t)N * 2048 * 2);  // aggregated features bf16
  float* hf32  = (float*)alloc((size_t)N * 1024 * 4);   // L3 GEMM out f32
  ushort* xb   = (ushort*)alloc((size_t)N * 256 * 2);
  __hip_bfloat16* Wt1 = (__hip_bfloat16*)alloc((size_t)2048 * 256 * 2);
  __hip_bfloat16* Wt2 = (__hip_bfloat16*)alloc((size_t)2048 * 2048 * 2);
  __hip_bfloat16* Wt3 = (__hip_bfloat16*)alloc((size_t)1024 * 2048 * 2);
  float* wa1s = (float*)alloc(256 * 4);
  float* wa1d = (float*)alloc(256 * 4);
  float* wa2s = (float*)alloc(2048 * 4);
  float* wa2d = (float*)alloc(2048 * 4);
  float* wa3s = (float*)alloc(2048 * 4);
  float* wa3d = (float*)alloc(2048 * 4);
  float* als1 = (float*)alloc((size_t)N * 4);
  float* ald1 = (float*)alloc((size_t)N * 4);
  // atomic accumulators (zeroed each call): als2, ald2, als3, ald3, ss
  float* alaux = (float*)alloc((size_t)N * 5 * 4);
  float* als2 = alaux;
  float* ald2 = alaux + N;
  float* als3 = alaux + 2 * (size_t)N;
  float* ald3 = alaux + 3 * (size_t)N;
  float* ssq  = alaux + 4 * (size_t)N;
  int* counts  = (int*)alloc((size_t)N * 4);
  int* rowptr  = (int*)alloc((size_t)(N + 1) * 4);
  int* cursor  = (int*)alloc((size_t)N * 4);
  int* eidx    = (int*)alloc((size_t)E * 4);

  const int* srcp = ei;
  const int* dstp = ei + E;

  hipFuncSetAttribute((const void*)gemm_t128<true, 1>,
                      hipFuncAttributeMaxDynamicSharedMemorySize, 32768);
  hipFuncSetAttribute((const void*)gemm_t128<false, 2>,
                      hipFuncAttributeMaxDynamicSharedMemorySize, 32768);

  // zero atomic accumulators + CSR counts (inside launch: replay-safe)
  hipMemsetAsync(alaux, 0, (size_t)N * 5 * 4, stream);
  hipMemsetAsync(counts, 0, (size_t)N * 4, stream);

  // CSR build (by dst)
  count_kernel<<<(E + 255) / 256, 256, 0, stream>>>(dstp, counts, E);
  scan_kernel<<<1, 1024, 0, stream>>>(counts, rowptr, cursor, N);
  fill_kernel<<<(E + 255) / 256, 256, 0, stream>>>(srcp, dstp, cursor, eidx, E);

  // prep: bf16 casts, weight transposes, wa matvecs
  convert_f32_bf16<<<(N * 256 + 255) / 256, 256, 0, stream>>>(x, (__hip_bfloat16*)xb, N * 256);
  transpose_w<<<dim3(2048 / 32, 256 / 32), 256, 0, stream>>>(W1, Wt1, 256, 2048);
  transpose_w<<<dim3(2048 / 32, 2048 / 32), 256, 0, stream>>>(W2, Wt2, 2048, 2048);
  transpose_w<<<dim3(1024 / 32, 2048 / 32), 256, 0, stream>>>(W3, Wt3, 2048, 1024);
  matvec_wa<<<256, 256, 0, stream>>>(W1, a1s, a1d, wa1s, wa1d, 2048);
  matvec_wa<<<2048, 256, 0, stream>>>(W2, a2s, a2d, wa2s, wa2d, 2048);
  matvec_wa<<<2048, 256, 0, stream>>>(W3, a3s, a3d, wa3s, wa3d, 1024);

  dim3 blk(256);
  int mb = (N + 127) / 128;  // 79

  // layer 1: al on x (F=256), agg, GEMM 256->2048 (+fused al for layer 2)
  compute_al1<<<N, blk, 0, stream>>>(xb, wa1s, wa1d, als1, ald1);
  aggregate<1><<<N, blk, 0, stream>>>(xb, als1, ald1, rowptr, eidx, hagg, 256);
  gemm_t128<true, 1><<<dim3(16, mb), blk, 32768, stream>>>(
      hagg, (const ushort*)Wt1, b1, h, wa2s, wa2d, als2, ald2, N, 256, 2048);

  // layer 2: agg, GEMM 2048->2048 (+fused al for layer 3)
  aggregate<8><<<N, blk, 0, stream>>>(h, als2, ald2, rowptr, eidx, hagg, 2048);
  gemm_t128<true, 1><<<dim3(16, mb), blk, 32768, stream>>>(
      hagg, (const ushort*)Wt2, b2, h, wa3s, wa3d, als3, ald3, N, 2048, 2048);

  // layer 3: agg, GEMM 2048->1024 f32 (+fused sum-of-squares)
  aggregate<8><<<N, blk, 0, stream>>>(h, als3, ald3, rowptr, eidx, hagg, 2048);
  gemm_t128<false, 2><<<dim3(8, mb), blk, 32768, stream>>>(
      hagg, (const ushort*)Wt3, b3, hf32, nullptr, nullptr, ssq, nullptr, N, 2048, 1024);

  // one-pass normalize using fused sum-of-squares
  normalize_ss<<<N, blk, 0, stream>>>(hf32, ssq, (float*)d_out, 1024);
}

// Round 15
// 458.753 us; speedup vs baseline: 1.0259x; 1.0259x over previous
//
#include <hip/hip_runtime.h>
#include <hip/hip_bf16.h>
#include <math.h>

// ---------------------------------------------------------------------------
// 3-layer GAT forward. Round 15: revert R14's epilogue fusion (cost > gain);
// per-layer best GEMM: L1/L3 = R13 gemm_t128 (128x128, 4 blk/CU, good tails),
// L2 = R11 gemm_p2 (256x128, 48KiB, vmcnt(3), measured 111us).
// matvec_wa fused into transpose_w (atomicAdd partial dots).
// edge_index read directly as int32.
// ---------------------------------------------------------------------------

typedef __attribute__((ext_vector_type(8))) short short8;
typedef __attribute__((ext_vector_type(4))) float f32x4;

#define GLOAD_LDS16(g, l)                                            \
  __builtin_amdgcn_global_load_lds(                                  \
      (const __attribute__((address_space(1))) void*)(g),            \
      (__attribute__((address_space(3))) void*)(l), 16, 0, 0)

#define CFENCE asm volatile("" ::: "memory")

__device__ __forceinline__ float bf16_to_f32(ushort u) {
  return __uint_as_float(((unsigned int)u) << 16);
}

__device__ __forceinline__ float block_reduce_sum_bcast(float v) {
#pragma unroll
  for (int off = 32; off > 0; off >>= 1) v += __shfl_down(v, off, 64);
  __shared__ float tmp[4];
  __shared__ float res;
  int lane = threadIdx.x & 63, w = threadIdx.x >> 6;
  if (lane == 0) tmp[w] = v;
  __syncthreads();
  if (threadIdx.x == 0) res = tmp[0] + tmp[1] + tmp[2] + tmp[3];
  __syncthreads();
  float out = res;
  __syncthreads();
  return out;
}

__device__ __forceinline__ float block_reduce_max_bcast(float v) {
#pragma unroll
  for (int off = 32; off > 0; off >>= 1) v = fmaxf(v, __shfl_down(v, off, 64));
  __shared__ float tmpm[4];
  __shared__ float resm;
  int lane = threadIdx.x & 63, w = threadIdx.x >> 6;
  if (lane == 0) tmpm[w] = v;
  __syncthreads();
  if (threadIdx.x == 0) resm = fmaxf(fmaxf(tmpm[0], tmpm[1]), fmaxf(tmpm[2], tmpm[3]));
  __syncthreads();
  float out = resm;
  __syncthreads();
  return out;
}

// ---------------------------------------------------------------------------
__global__ __launch_bounds__(256) void convert_f32_bf16(const float* __restrict__ in,
                                                        __hip_bfloat16* __restrict__ out,
                                                        int n) {
  int i = blockIdx.x * blockDim.x + threadIdx.x;
  if (i < n) out[i] = __float2bfloat16(in[i]);
}

// ---------------------------------------------------------------------------
// Transpose W [K][N] f32 -> Wt [N][K] bf16, 32x32 tiles, 256 threads,
// WITH fused wa partial dots: wa_s[k] += sum_n W[k][n]*a_s[n] (atomicAdd,
// wa pre-zeroed). Thread (tx,ty) holds W[k0+ty+8i][n0+tx]; reduce over tx
// (32-lane shfl groups), lane tx==0 adds.
// ---------------------------------------------------------------------------
__global__ __launch_bounds__(256) void transpose_w_fused(const float* __restrict__ W,
                                                         const float* __restrict__ a_s,
                                                         const float* __restrict__ a_d,
                                                         __hip_bfloat16* __restrict__ Wt,
                                                         float* __restrict__ wa_s,
                                                         float* __restrict__ wa_d,
                                                         int K, int Nout) {
  __shared__ float t[32][33];
  int tx = threadIdx.x & 31, ty = threadIdx.x >> 5;  // 32 x 8
  int n0 = blockIdx.x * 32, k0 = blockIdx.y * 32;
  float as = a_s[n0 + tx], ad = a_d[n0 + tx];
#pragma unroll
  for (int i = 0; i < 4; ++i) {
    int k = k0 + ty + i * 8;
    float wv = W[(size_t)k * Nout + n0 + tx];
    t[ty + i * 8][tx] = wv;
    float pS = wv * as, pD = wv * ad;
#pragma unroll
    for (int off = 1; off < 32; off <<= 1) {
      pS += __shfl_xor(pS, off, 64);
      pD += __shfl_xor(pD, off, 64);
    }
    if (tx == 0) {
      atomicAdd(&wa_s[k], pS);
      atomicAdd(&wa_d[k], pD);
    }
  }
  __syncthreads();
#pragma unroll
  for (int i = 0; i < 4; ++i) {
    int n = n0 + ty + i * 8;
    Wt[(size_t)n * K + k0 + tx] = __float2bfloat16(t[tx][ty + i * 8]);
  }
}

// ---------------------------------------------------------------------------
// als[n] = dot(H[n,:], wa_s); ald[n] = dot(H[n,:], wa_d).  H bf16 [N][F].
// ---------------------------------------------------------------------------
template <int FPT>
__global__ __launch_bounds__(256) void compute_al(const ushort* __restrict__ H,
                                                  const float* __restrict__ wa_s,
                                                  const float* __restrict__ wa_d,
                                                  float* __restrict__ als,
                                                  float* __restrict__ ald, int F) {
  int n = blockIdx.x;
  const ushort* row = H + (size_t)n * F;
  float s1 = 0.f, s2 = 0.f;
  if (FPT == 8) {
    int base = threadIdx.x * 8;
    short8 v = *(const short8*)(row + base);
#pragma unroll
    for (int j = 0; j < 8; ++j) {
      float f = bf16_to_f32((ushort)v[j]);
      s1 += f * wa_s[base + j];
      s2 += f * wa_d[base + j];
    }
  } else {
    float f = bf16_to_f32(row[threadIdx.x]);
    s1 = f * wa_s[threadIdx.x];
    s2 = f * wa_d[threadIdx.x];
  }
  float r1 = block_reduce_sum_bcast(s1);
  float r2 = block_reduce_sum_bcast(s2);
  if (threadIdx.x == 0) {
    als[n] = r1;
    ald[n] = r2;
  }
}

// ---------------------------------------------------------------------------
// CSR build (edge_index int32: [2][E], src then dst)
// ---------------------------------------------------------------------------
__global__ void count_kernel(const int* __restrict__ dst, int* __restrict__ counts, int E) {
  int i = blockIdx.x * blockDim.x + threadIdx.x;
  if (i < E) atomicAdd(&counts[dst[i]], 1);
}

__global__ __launch_bounds__(1024) void scan_kernel(const int* __restrict__ counts,
                                                    int* __restrict__ rowptr,
                                                    int* __restrict__ cursor, int Nn) {
  __shared__ int part[1024];
  int tid = threadIdx.x;
  int chunk = (Nn + 1023) / 1024;
  int base = tid * chunk;
  int s = 0;
  for (int i = 0; i < chunk; ++i) {
    int idx = base + i;
    if (idx < Nn) s += counts[idx];
  }
  part[tid] = s;
  __syncthreads();
  for (int off = 1; off < 1024; off <<= 1) {
    int v = 0;
    if (tid >= off) v = part[tid - off];
    __syncthreads();
    if (tid >= off) part[tid] += v;
    __syncthreads();
  }
  int run = (tid == 0) ? 0 : part[tid - 1];
  for (int i = 0; i < chunk; ++i) {
    int idx = base + i;
    if (idx < Nn) {
      rowptr[idx] = run;
      cursor[idx] = run;
      run += counts[idx];
    }
  }
  if (tid == 1023) rowptr[Nn] = part[1023];
}

__global__ void fill_kernel(const int* __restrict__ src, const int* __restrict__ dst,
                            int* __restrict__ cursor, int* __restrict__ eidx, int E) {
  int i = blockIdx.x * blockDim.x + threadIdx.x;
  if (i < E) {
    int pos = atomicAdd(&cursor[dst[i]], 1);
    eidx[pos] = src[i];
  }
}

// ---------------------------------------------------------------------------
// H_agg[n] = sum_e alpha_e * H_in[src_e]  (softmax attention, self-loop incl).
// ---------------------------------------------------------------------------
template <int FPT>
__global__ __launch_bounds__(256) void aggregate(const ushort* __restrict__ H,
                                                 const float* __restrict__ als,
                                                 const float* __restrict__ ald,
                                                 const int* __restrict__ rowptr,
                                                 const int* __restrict__ eidx,
                                                 ushort* __restrict__ out, int F) {
  int n = blockIdx.x;
  int tid = threadIdx.x;
  int beg = rowptr[n], end = rowptr[n + 1];
  int deg = end - beg;
  float aldn = ald[n];

  float lm = -INFINITY;
  for (int j = tid; j < deg; j += 256) {
    int s = eidx[beg + j];
    float e = als[s] + aldn;
    e = (e > 0.f) ? e : 0.2f * e;
    lm = fmaxf(lm, e);
  }
  if (tid == 0) {
    float e = als[n] + aldn;
    e = (e > 0.f) ? e : 0.2f * e;
    lm = fmaxf(lm, e);
  }
  float m = block_reduce_max_bcast(lm);

  float ls = 0.f;
  for (int j = tid; j < deg; j += 256) {
    int s = eidx[beg + j];
    float e = als[s] + aldn;
    e = (e > 0.f) ? e : 0.2f * e;
    ls += expf(e - m);
  }
  if (tid == 0) {
    float e = als[n] + aldn;
    e = (e > 0.f) ? e : 0.2f * e;
    ls += expf(e - m);
  }
  float denom = block_reduce_sum_bcast(ls) + 1e-16f;
  float inv_denom = 1.f / denom;

  float acc[FPT];
#pragma unroll
  for (int i = 0; i < FPT; ++i) acc[i] = 0.f;

  __shared__ float alpha_sh[256];
  __shared__ int src_sh[256];
  int total = deg + 1;
  for (int c0 = 0; c0 < total; c0 += 256) {
    int j = c0 + tid;
    if (j < total) {
      int s = (j < deg) ? eidx[beg + j] : n;
      float e = als[s] + aldn;
      e = (e > 0.f) ? e : 0.2f * e;
      alpha_sh[tid] = expf(e - m) * inv_denom;
      src_sh[tid] = s;
    }
    __syncthreads();
    int cn = min(256, total - c0);
    for (int jj = 0; jj < cn; ++jj) {
      float al = alpha_sh[jj];
      const ushort* row = H + (size_t)src_sh[jj] * F;
      if (FPT == 1) {
        acc[0] += al * bf16_to_f32(row[tid]);
      } else {
#pragma unroll
        for (int i = 0; i < FPT / 2; ++i) {
          unsigned int u = *(const unsigned int*)(row + tid * 2 + i * 512);
          acc[2 * i]     += al * __uint_as_float((u & 0xffffu) << 16);
          acc[2 * i + 1] += al * __uint_as_float(u & 0xffff0000u);
        }
      }
    }
    __syncthreads();
  }

#pragma unroll
  for (int i = 0; i < FPT; ++i) {
    int col = (FPT == 1) ? tid : (tid * 2 + (i >> 1) * 512 + (i & 1));
    __hip_bfloat16 hv = __float2bfloat16(acc[i]);
    out[(size_t)n * F + col] = *(ushort*)&hv;
  }
}

// ---------------------------------------------------------------------------
// GEMM variant A (L1/L3): 128x128, 4 waves, 2 buf (32 KiB), vmcnt(4), (256,4).
// ---------------------------------------------------------------------------
template <bool BF16OUT>
__global__ __launch_bounds__(256, 4) void gemm_t128(const ushort* __restrict__ A,
                                                    const ushort* __restrict__ Bt,
                                                    const float* __restrict__ bias,
                                                    void* __restrict__ C,
                                                    int M, int K, int Nout) {
  constexpr int BUF = 8192;
  extern __shared__ ushort lds[];
  const int tid = threadIdx.x;
  const int l = tid & 63, w = tid >> 6;
  const int wm = w >> 1, wn = w & 1;
  const int l15 = l & 15, lhi = l >> 4;

  int nwg = gridDim.x * gridDim.y;
  int lin = blockIdx.y * gridDim.x + blockIdx.x;
  if ((nwg & 7) == 0) lin = (lin & 7) * (nwg >> 3) + (lin >> 3);
  const int bx = lin % gridDim.x, by = lin / gridDim.x;
  const int row0 = by * 128, col0 = bx * 128;

  const int c8sw = (l & 3) ^ (((l >> 5) & 1) << 1);
  const int lrow = l >> 2;
  const int chsw = lhi ^ (((l15 >> 3) & 1) << 1);
  const int rd_off = l15 * 32 + chsw * 8;

  const int sA0 = w * 2;
  const ushort* ga[2];
  const ushort* gb[2];
#pragma unroll
  for (int j = 0; j < 2; ++j) {
    int ar = min(row0 + (sA0 + j) * 16 + lrow, M - 1);
    ga[j] = A + (size_t)ar * K + c8sw * 8;
    gb[j] = Bt + (size_t)(col0 + (sA0 + j) * 16 + lrow) * K + c8sw * 8;
  }

#define STAGE(nb, kn)                                                     \
  do {                                                                    \
    GLOAD_LDS16(ga[0] + (kn), &lds[(nb)*BUF + (sA0 + 0) * 512]);          \
    GLOAD_LDS16(ga[1] + (kn), &lds[(nb)*BUF + (sA0 + 1) * 512]);          \
    GLOAD_LDS16(gb[0] + (kn), &lds[(nb)*BUF + 4096 + (sA0 + 0) * 512]);   \
    GLOAD_LDS16(gb[1] + (kn), &lds[(nb)*BUF + 4096 + (sA0 + 1) * 512]);   \
  } while (0)

  f32x4 acc[4][4] = {};

#define PHASE(cur, WAITLIT, STAGE_STMT)                                              \
  do {                                                                               \
    STAGE_STMT;                                                                      \
    asm volatile("s_waitcnt vmcnt(" WAITLIT ")" ::: "memory");                       \
    __builtin_amdgcn_s_barrier();                                                    \
    CFENCE;                                                                          \
    short8 af[4], bf[4];                                                             \
    const ushort* Ab = &lds[(cur)*BUF];                                              \
    const ushort* Bb = &lds[(cur)*BUF + 4096];                                       \
    _Pragma("unroll") for (int m = 0; m < 4; ++m)                                    \
        af[m] = *(const short8*)(Ab + (wm * 4 + m) * 512 + rd_off);                  \
    _Pragma("unroll") for (int n = 0; n < 4; ++n)                                    \
        bf[n] = *(const short8*)(Bb + (wn * 4 + n) * 512 + rd_off);                  \
    __builtin_amdgcn_s_setprio(1);                                                   \
    _Pragma("unroll") for (int m = 0; m < 4; ++m)                                    \
        _Pragma("unroll") for (int n = 0; n < 4; ++n)                                \
            acc[m][n] = __builtin_amdgcn_mfma_f32_16x16x32_bf16(                     \
                af[m], bf[n], acc[m][n], 0, 0, 0);                                   \
    __builtin_amdgcn_s_setprio(0);                                                   \
    CFENCE;                                                                          \
    __builtin_amdgcn_s_barrier();                                                    \
    CFENCE;                                                                          \
  } while (0)

  const int nt = K >> 5;
  STAGE(0, 0);
  int cur = 0;
  for (int t = 0; t < nt - 1; ++t) {
    const int kn = (t + 1) << 5;
    PHASE(cur, "4", STAGE(cur ^ 1, kn));
    cur ^= 1;
  }
  PHASE(cur, "0", );

#pragma unroll
  for (int mi = 0; mi < 4; ++mi) {
#pragma unroll
    for (int v = 0; v < 4; ++v) {
      int r = row0 + wm * 64 + mi * 16 + lhi * 4 + v;
      if (r < M) {
#pragma unroll
        for (int n = 0; n < 4; ++n) {
          int col = col0 + wn * 64 + n * 16 + l15;
          float val = fmaxf(acc[mi][n][v] + bias[col], 0.f);
          size_t idx = (size_t)r * Nout + col;
          if (BF16OUT)
            ((__hip_bfloat16*)C)[idx] = __float2bfloat16(val);
          else
            ((float*)C)[idx] = val;
        }
      }
    }
  }
#undef PHASE
#undef STAGE
}

// ---------------------------------------------------------------------------
// GEMM variant B (L2): 256x128, 8 waves, 2 buf (48 KiB), vmcnt(3), (512,4).
// ---------------------------------------------------------------------------
template <bool BF16OUT>
__global__ __launch_bounds__(512, 4) void gemm_p2(const ushort* __restrict__ A,
                                                  const ushort* __restrict__ Bt,
                                                  const float* __restrict__ bias,
                                                  void* __restrict__ C,
                                                  int M, int K, int Nout) {
  constexpr int BUF = 12288;
  extern __shared__ ushort lds[];
  const int tid = threadIdx.x;
  const int l = tid & 63, w = tid >> 6;
  const int wm = w >> 2, wn = w & 3;
  const int l15 = l & 15, lhi = l >> 4;

  int nwg = gridDim.x * gridDim.y;
  int lin = blockIdx.y * gridDim.x + blockIdx.x;
  if ((nwg & 7) == 0) lin = (lin & 7) * (nwg >> 3) + (lin >> 3);
  const int bx = lin % gridDim.x, by = lin / gridDim.x;
  const int row0 = by * 256, col0 = bx * 128;

  const int c8sw = (l & 3) ^ (((l >> 5) & 1) << 1);
  const int lrow = l >> 2;
  const int chsw = lhi ^ (((l15 >> 3) & 1) << 1);
  const int rd_off = l15 * 32 + chsw * 8;

  const int sA0 = w * 2;
  const int sB0 = w;
  const ushort* ga[2];
  const ushort* gb;
#pragma unroll
  for (int j = 0; j < 2; ++j) {
    int ar = min(row0 + (sA0 + j) * 16 + lrow, M - 1);
    ga[j] = A + (size_t)ar * K + c8sw * 8;
  }
  gb = Bt + (size_t)(col0 + sB0 * 16 + lrow) * K + c8sw * 8;

#define STAGE(nb, kn)                                               \
  do {                                                              \
    GLOAD_LDS16(ga[0] + (kn), &lds[(nb)*BUF + (sA0 + 0) * 512]);    \
    GLOAD_LDS16(ga[1] + (kn), &lds[(nb)*BUF + (sA0 + 1) * 512]);    \
    GLOAD_LDS16(gb + (kn), &lds[(nb)*BUF + 8192 + sB0 * 512]);      \
  } while (0)

  f32x4 acc[8][2] = {};

#define PHASE(cur, WAITLIT, STAGE_STMT)                                              \
  do {                                                                               \
    STAGE_STMT;                                                                      \
    asm volatile("s_waitcnt vmcnt(" WAITLIT ")" ::: "memory");                       \
    __builtin_amdgcn_s_barrier();                                                    \
    CFENCE;                                                                          \
    short8 af[8], bf[2];                                                             \
    const ushort* Ab = &lds[(cur)*BUF];                                              \
    const ushort* Bb = &lds[(cur)*BUF + 8192];                                       \
    _Pragma("unroll") for (int m = 0; m < 8; ++m)                                    \
        af[m] = *(const short8*)(Ab + (wm * 8 + m) * 512 + rd_off);                  \
    _Pragma("unroll") for (int n = 0; n < 2; ++n)                                    \
        bf[n] = *(const short8*)(Bb + (wn * 2 + n) * 512 + rd_off);                  \
    __builtin_amdgcn_s_setprio(1);                                                   \
    _Pragma("unroll") for (int m = 0; m < 8; ++m)                                    \
        _Pragma("unroll") for (int n = 0; n < 2; ++n)                                \
            acc[m][n] = __builtin_amdgcn_mfma_f32_16x16x32_bf16(                     \
                af[m], bf[n], acc[m][n], 0, 0, 0);                                   \
    __builtin_amdgcn_s_setprio(0);                                                   \
    CFENCE;                                                                          \
    __builtin_amdgcn_s_barrier();                                                    \
    CFENCE;                                                                          \
  } while (0)

  const int nt = K >> 5;
  STAGE(0, 0);
  int cur = 0;
  for (int t = 0; t < nt - 1; ++t) {
    const int kn = (t + 1) << 5;
    PHASE(cur, "3", STAGE(cur ^ 1, kn));
    cur ^= 1;
  }
  PHASE(cur, "0", );

#pragma unroll
  for (int mi = 0; mi < 8; ++mi) {
#pragma unroll
    for (int v = 0; v < 4; ++v) {
      int r = row0 + wm * 128 + mi * 16 + lhi * 4 + v;
      if (r < M) {
#pragma unroll
        for (int n = 0; n < 2; ++n) {
          int col = col0 + wn * 32 + n * 16 + l15;
          float val = fmaxf(acc[mi][n][v] + bias[col], 0.f);
          size_t idx = (size_t)r * Nout + col;
          if (BF16OUT)
            ((__hip_bfloat16*)C)[idx] = __float2bfloat16(val);
          else
            ((float*)C)[idx] = val;
        }
      }
    }
  }
#undef PHASE
#undef STAGE
}

// ---------------------------------------------------------------------------
// Row L2 normalize (eps 1e-12), f32 in, f32 out.
// ---------------------------------------------------------------------------
__global__ __launch_bounds__(256) void normalize_kernel(const float* __restrict__ h,
                                                        float* __restrict__ out,
                                                        int F) {
  int n = blockIdx.x;
  const float* row = h + (size_t)n * F;
  float ss = 0.f;
  for (int f = threadIdx.x; f < F; f += 256) {
    float v = row[f];
    ss += v * v;
  }
  float tot = block_reduce_sum_bcast(ss);
  float inv = 1.f / fmaxf(sqrtf(tot), 1e-12f);
  for (int f = threadIdx.x; f < F; f += 256) {
    out[(size_t)n * F + f] = row[f] * inv;
  }
}

// ---------------------------------------------------------------------------
extern "C" void kernel_launch(void* const* d_in, const int* in_sizes, int n_in,
                              void* d_out, int out_size, void* d_ws, size_t ws_size,
                              hipStream_t stream) {
  const float* x   = (const float*)d_in[0];
  const int*   ei  = (const int*)d_in[1];
  const float* W1  = (const float*)d_in[2];
  const float* W2  = (const float*)d_in[3];
  const float* W3  = (const float*)d_in[4];
  const float* a1s = (const float*)d_in[5];
  const float* a1d = (const float*)d_in[6];
  const float* a2s = (const float*)d_in[7];
  const float* a2d = (const float*)d_in[8];
  const float* a3s = (const float*)d_in[9];
  const float* a3d = (const float*)d_in[10];
  const float* b1  = (const float*)d_in[11];
  const float* b2  = (const float*)d_in[12];
  const float* b3  = (const float*)d_in[13];

  const int N = in_sizes[0] / 256;  // 10000
  const int E = in_sizes[1] / 2;    // 80000

  char* ws = (char*)d_ws;
  size_t off = 0;
  auto alloc = [&](size_t bytes) -> void* {
    void* p = ws + off;
    off += (bytes + 255) & ~(size_t)255;
    return p;
  };
  ushort* h    = (ushort*)alloc((size_t)N * 2048 * 2);
  ushort* hagg = (ushort*)alloc((size_t)N * 2048 * 2);
  float* hf32  = (float*)alloc((size_t)N * 1024 * 4);
  ushort* xb   = (ushort*)alloc((size_t)N * 256 * 2);
  __hip_bfloat16* Wt1 = (__hip_bfloat16*)alloc((size_t)2048 * 256 * 2);
  __hip_bfloat16* Wt2 = (__hip_bfloat16*)alloc((size_t)2048 * 2048 * 2);
  __hip_bfloat16* Wt3 = (__hip_bfloat16*)alloc((size_t)1024 * 2048 * 2);
  // wa buffers contiguous (atomic targets, zeroed each call):
  // wa1s[256] wa1d[256] wa2s[2048] wa2d[2048] wa3s[2048] wa3d[2048]
  float* wabuf = (float*)alloc((size_t)(256 * 2 + 2048 * 4) * 4);
  float* wa1s = wabuf;
  float* wa1d = wabuf + 256;
  float* wa2s = wabuf + 512;
  float* wa2d = wabuf + 512 + 2048;
  float* wa3s = wabuf + 512 + 2 * 2048;
  float* wa3d = wabuf + 512 + 3 * 2048;
  float* als   = (float*)alloc((size_t)N * 4);
  float* ald   = (float*)alloc((size_t)N * 4);
  int* counts  = (int*)alloc((size_t)N * 4);
  int* rowptr  = (int*)alloc((size_t)(N + 1) * 4);
  int* cursor  = (int*)alloc((size_t)N * 4);
  int* eidx    = (int*)alloc((size_t)E * 4);

  const int* srcp = ei;
  const int* dstp = ei + E;

  hipFuncSetAttribute((const void*)gemm_t128<true>,
                      hipFuncAttributeMaxDynamicSharedMemorySize, 32768);
  hipFuncSetAttribute((const void*)gemm_t128<false>,
                      hipFuncAttributeMaxDynamicSharedMemorySize, 32768);
  hipFuncSetAttribute((const void*)gemm_p2<true>,
                      hipFuncAttributeMaxDynamicSharedMemorySize, 49152);

  // zero wa accumulators + CSR counts (inside launch: replay-safe)
  hipMemsetAsync(wabuf, 0, (size_t)(256 * 2 + 2048 * 4) * 4, stream);
  hipMemsetAsync(counts, 0, (size_t)N * 4, stream);

  // CSR build (by dst)
  count_kernel<<<(E + 255) / 256, 256, 0, stream>>>(dstp, counts, E);
  scan_kernel<<<1, 1024, 0, stream>>>(counts, rowptr, cursor, N);
  fill_kernel<<<(E + 255) / 256, 256, 0, stream>>>(srcp, dstp, cursor, eidx, E);

  // prep: bf16 cast + fused transpose/wa
  convert_f32_bf16<<<(N * 256 + 255) / 256, 256, 0, stream>>>(x, (__hip_bfloat16*)xb, N * 256);
  transpose_w_fused<<<dim3(2048 / 32, 256 / 32), 256, 0, stream>>>(W1, a1s, a1d, Wt1, wa1s, wa1d, 256, 2048);
  transpose_w_fused<<<dim3(2048 / 32, 2048 / 32), 256, 0, stream>>>(W2, a2s, a2d, Wt2, wa2s, wa2d, 2048, 2048);
  transpose_w_fused<<<dim3(1024 / 32, 2048 / 32), 256, 0, stream>>>(W3, a3s, a3d, Wt3, wa3s, wa3d, 2048, 1024);

  dim3 blk(256);
  dim3 gblk(512);
  int mb128 = (N + 127) / 128;  // 79
  int mb256 = (N + 255) / 256;  // 40

  // layer 1: al on x (F=256), agg, GEMM 256->2048 (t128, grid 16x79)
  compute_al<1><<<N, blk, 0, stream>>>(xb, wa1s, wa1d, als, ald, 256);
  aggregate<1><<<N, blk, 0, stream>>>(xb, als, ald, rowptr, eidx, hagg, 256);
  gemm_t128<true><<<dim3(16, mb128), blk, 32768, stream>>>(hagg, (const ushort*)Wt1, b1, h, N, 256, 2048);

  // layer 2: al, agg, GEMM 2048->2048 (p2, grid 16x40)
  compute_al<8><<<N, blk, 0, stream>>>(h, wa2s, wa2d, als, ald, 2048);
  aggregate<8><<<N, blk, 0, stream>>>(h, als, ald, rowptr, eidx, hagg, 2048);
  gemm_p2<true><<<dim3(16, mb256), gblk, 49152, stream>>>(hagg, (const ushort*)Wt2, b2, h, N, 2048, 2048);

  // layer 3: al, agg, GEMM 2048->1024 f32 (t128, grid 8x79)
  compute_al<8><<<N, blk, 0, stream>>>(h, wa3s, wa3d, als, ald, 2048);
  aggregate<8><<<N, blk, 0, stream>>>(h, als, ald, rowptr, eidx, hagg, 2048);
  gemm_t128<false><<<dim3(8, mb128), blk, 32768, stream>>>(hagg, (const ushort*)Wt3, b3, hf32, N, 2048, 1024);

  normalize_kernel<<<N, blk, 0, stream>>>(hf32, (float*)d_out, 1024);
}

// Round 16
// 426.293 us; speedup vs baseline: 1.1040x; 1.0761x over previous
//
#include <hip/hip_runtime.h>
#include <hip/hip_bf16.h>
#include <math.h>

// ---------------------------------------------------------------------------
// 3-layer GAT forward. Round 16: R13 (best, 428.7us) + single change:
// L2 GEMM = gemm_p2 (256x128, 48KiB, vmcnt(3)) — measured ~112us vs t128's
// 119 in both R11 and R15. All fusions reverted (R14/R15 both showed
// inner-loop fusion costs > saved passes). edge_index read as int32.
// ---------------------------------------------------------------------------

typedef __attribute__((ext_vector_type(8))) short short8;
typedef __attribute__((ext_vector_type(4))) float f32x4;

#define GLOAD_LDS16(g, l)                                            \
  __builtin_amdgcn_global_load_lds(                                  \
      (const __attribute__((address_space(1))) void*)(g),            \
      (__attribute__((address_space(3))) void*)(l), 16, 0, 0)

#define CFENCE asm volatile("" ::: "memory")

__device__ __forceinline__ float bf16_to_f32(ushort u) {
  return __uint_as_float(((unsigned int)u) << 16);
}

__device__ __forceinline__ float block_reduce_sum_bcast(float v) {
#pragma unroll
  for (int off = 32; off > 0; off >>= 1) v += __shfl_down(v, off, 64);
  __shared__ float tmp[4];
  __shared__ float res;
  int lane = threadIdx.x & 63, w = threadIdx.x >> 6;
  if (lane == 0) tmp[w] = v;
  __syncthreads();
  if (threadIdx.x == 0) res = tmp[0] + tmp[1] + tmp[2] + tmp[3];
  __syncthreads();
  float out = res;
  __syncthreads();
  return out;
}

__device__ __forceinline__ float block_reduce_max_bcast(float v) {
#pragma unroll
  for (int off = 32; off > 0; off >>= 1) v = fmaxf(v, __shfl_down(v, off, 64));
  __shared__ float tmpm[4];
  __shared__ float resm;
  int lane = threadIdx.x & 63, w = threadIdx.x >> 6;
  if (lane == 0) tmpm[w] = v;
  __syncthreads();
  if (threadIdx.x == 0) resm = fmaxf(fmaxf(tmpm[0], tmpm[1]), fmaxf(tmpm[2], tmpm[3]));
  __syncthreads();
  float out = resm;
  __syncthreads();
  return out;
}

// ---------------------------------------------------------------------------
__global__ __launch_bounds__(256) void convert_f32_bf16(const float* __restrict__ in,
                                                        __hip_bfloat16* __restrict__ out,
                                                        int n) {
  int i = blockIdx.x * blockDim.x + threadIdx.x;
  if (i < n) out[i] = __float2bfloat16(in[i]);
}

// ---------------------------------------------------------------------------
// Transpose W [K][N] f32 -> Wt [N][K] bf16.  32x32 tiles, 256 threads.
// ---------------------------------------------------------------------------
__global__ __launch_bounds__(256) void transpose_w(const float* __restrict__ W,
                                                   __hip_bfloat16* __restrict__ Wt,
                                                   int K, int Nout) {
  __shared__ float t[32][33];
  int tx = threadIdx.x & 31, ty = threadIdx.x >> 5;  // 32 x 8
  int n0 = blockIdx.x * 32, k0 = blockIdx.y * 32;
#pragma unroll
  for (int i = 0; i < 4; ++i) {
    int k = k0 + ty + i * 8;
    t[ty + i * 8][tx] = W[(size_t)k * Nout + n0 + tx];
  }
  __syncthreads();
#pragma unroll
  for (int i = 0; i < 4; ++i) {
    int n = n0 + ty + i * 8;
    Wt[(size_t)n * K + k0 + tx] = __float2bfloat16(t[tx][ty + i * 8]);
  }
}

// ---------------------------------------------------------------------------
// wa_s[k] = sum_f W[k][f] * a_s[f];  wa_d likewise.  W row-major [K][F] f32.
// ---------------------------------------------------------------------------
__global__ __launch_bounds__(256) void matvec_wa(const float* __restrict__ W,
                                                 const float* __restrict__ a_s,
                                                 const float* __restrict__ a_d,
                                                 float* __restrict__ wa_s,
                                                 float* __restrict__ wa_d, int F) {
  int k = blockIdx.x;
  const float* row = W + (size_t)k * F;
  float s1 = 0.f, s2 = 0.f;
  for (int f = threadIdx.x; f < F; f += 256) {
    float w = row[f];
    s1 += w * a_s[f];
    s2 += w * a_d[f];
  }
  float r1 = block_reduce_sum_bcast(s1);
  float r2 = block_reduce_sum_bcast(s2);
  if (threadIdx.x == 0) {
    wa_s[k] = r1;
    wa_d[k] = r2;
  }
}

// ---------------------------------------------------------------------------
// als[n] = dot(H[n,:], wa_s); ald[n] = dot(H[n,:], wa_d).  H bf16 [N][F].
// ---------------------------------------------------------------------------
template <int FPT>
__global__ __launch_bounds__(256) void compute_al(const ushort* __restrict__ H,
                                                  const float* __restrict__ wa_s,
                                                  const float* __restrict__ wa_d,
                                                  float* __restrict__ als,
                                                  float* __restrict__ ald, int F) {
  int n = blockIdx.x;
  const ushort* row = H + (size_t)n * F;
  float s1 = 0.f, s2 = 0.f;
  if (FPT == 8) {
    int base = threadIdx.x * 8;
    short8 v = *(const short8*)(row + base);
#pragma unroll
    for (int j = 0; j < 8; ++j) {
      float f = bf16_to_f32((ushort)v[j]);
      s1 += f * wa_s[base + j];
      s2 += f * wa_d[base + j];
    }
  } else {
    float f = bf16_to_f32(row[threadIdx.x]);
    s1 = f * wa_s[threadIdx.x];
    s2 = f * wa_d[threadIdx.x];
  }
  float r1 = block_reduce_sum_bcast(s1);
  float r2 = block_reduce_sum_bcast(s2);
  if (threadIdx.x == 0) {
    als[n] = r1;
    ald[n] = r2;
  }
}

// ---------------------------------------------------------------------------
// CSR build (edge_index int32: [2][E], src then dst)
// ---------------------------------------------------------------------------
__global__ void count_kernel(const int* __restrict__ dst, int* __restrict__ counts, int E) {
  int i = blockIdx.x * blockDim.x + threadIdx.x;
  if (i < E) atomicAdd(&counts[dst[i]], 1);
}

__global__ __launch_bounds__(1024) void scan_kernel(const int* __restrict__ counts,
                                                    int* __restrict__ rowptr,
                                                    int* __restrict__ cursor, int Nn) {
  __shared__ int part[1024];
  int tid = threadIdx.x;
  int chunk = (Nn + 1023) / 1024;
  int base = tid * chunk;
  int s = 0;
  for (int i = 0; i < chunk; ++i) {
    int idx = base + i;
    if (idx < Nn) s += counts[idx];
  }
  part[tid] = s;
  __syncthreads();
  for (int off = 1; off < 1024; off <<= 1) {
    int v = 0;
    if (tid >= off) v = part[tid - off];
    __syncthreads();
    if (tid >= off) part[tid] += v;
    __syncthreads();
  }
  int run = (tid == 0) ? 0 : part[tid - 1];
  for (int i = 0; i < chunk; ++i) {
    int idx = base + i;
    if (idx < Nn) {
      rowptr[idx] = run;
      cursor[idx] = run;
      run += counts[idx];
    }
  }
  if (tid == 1023) rowptr[Nn] = part[1023];
}

__global__ void fill_kernel(const int* __restrict__ src, const int* __restrict__ dst,
                            int* __restrict__ cursor, int* __restrict__ eidx, int E) {
  int i = blockIdx.x * blockDim.x + threadIdx.x;
  if (i < E) {
    int pos = atomicAdd(&cursor[dst[i]], 1);
    eidx[pos] = src[i];
  }
}

// ---------------------------------------------------------------------------
// H_agg[n] = sum_e alpha_e * H_in[src_e]  (softmax attention, self-loop incl).
// ---------------------------------------------------------------------------
template <int FPT>
__global__ __launch_bounds__(256) void aggregate(const ushort* __restrict__ H,
                                                 const float* __restrict__ als,
                                                 const float* __restrict__ ald,
                                                 const int* __restrict__ rowptr,
                                                 const int* __restrict__ eidx,
                                                 ushort* __restrict__ out, int F) {
  int n = blockIdx.x;
  int tid = threadIdx.x;
  int beg = rowptr[n], end = rowptr[n + 1];
  int deg = end - beg;
  float aldn = ald[n];

  float lm = -INFINITY;
  for (int j = tid; j < deg; j += 256) {
    int s = eidx[beg + j];
    float e = als[s] + aldn;
    e = (e > 0.f) ? e : 0.2f * e;
    lm = fmaxf(lm, e);
  }
  if (tid == 0) {
    float e = als[n] + aldn;
    e = (e > 0.f) ? e : 0.2f * e;
    lm = fmaxf(lm, e);
  }
  float m = block_reduce_max_bcast(lm);

  float ls = 0.f;
  for (int j = tid; j < deg; j += 256) {
    int s = eidx[beg + j];
    float e = als[s] + aldn;
    e = (e > 0.f) ? e : 0.2f * e;
    ls += expf(e - m);
  }
  if (tid == 0) {
    float e = als[n] + aldn;
    e = (e > 0.f) ? e : 0.2f * e;
    ls += expf(e - m);
  }
  float denom = block_reduce_sum_bcast(ls) + 1e-16f;
  float inv_denom = 1.f / denom;

  float acc[FPT];
#pragma unroll
  for (int i = 0; i < FPT; ++i) acc[i] = 0.f;

  __shared__ float alpha_sh[256];
  __shared__ int src_sh[256];
  int total = deg + 1;
  for (int c0 = 0; c0 < total; c0 += 256) {
    int j = c0 + tid;
    if (j < total) {
      int s = (j < deg) ? eidx[beg + j] : n;
      float e = als[s] + aldn;
      e = (e > 0.f) ? e : 0.2f * e;
      alpha_sh[tid] = expf(e - m) * inv_denom;
      src_sh[tid] = s;
    }
    __syncthreads();
    int cn = min(256, total - c0);
    for (int jj = 0; jj < cn; ++jj) {
      float al = alpha_sh[jj];
      const ushort* row = H + (size_t)src_sh[jj] * F;
      if (FPT == 1) {
        acc[0] += al * bf16_to_f32(row[tid]);
      } else {
#pragma unroll
        for (int i = 0; i < FPT / 2; ++i) {
          unsigned int u = *(const unsigned int*)(row + tid * 2 + i * 512);
          acc[2 * i]     += al * __uint_as_float((u & 0xffffu) << 16);
          acc[2 * i + 1] += al * __uint_as_float(u & 0xffff0000u);
        }
      }
    }
    __syncthreads();
  }

#pragma unroll
  for (int i = 0; i < FPT; ++i) {
    int col = (FPT == 1) ? tid : (tid * 2 + (i >> 1) * 512 + (i & 1));
    __hip_bfloat16 hv = __float2bfloat16(acc[i]);
    out[(size_t)n * F + col] = *(ushort*)&hv;
  }
}

// ---------------------------------------------------------------------------
// GEMM variant A (L1/L3): 128x128, 4 waves, 2 buf (32 KiB), vmcnt(4), (256,4).
// ---------------------------------------------------------------------------
template <bool BF16OUT>
__global__ __launch_bounds__(256, 4) void gemm_t128(const ushort* __restrict__ A,
                                                    const ushort* __restrict__ Bt,
                                                    const float* __restrict__ bias,
                                                    void* __restrict__ C,
                                                    int M, int K, int Nout) {
  constexpr int BUF = 8192;
  extern __shared__ ushort lds[];
  const int tid = threadIdx.x;
  const int l = tid & 63, w = tid >> 6;
  const int wm = w >> 1, wn = w & 1;
  const int l15 = l & 15, lhi = l >> 4;

  int nwg = gridDim.x * gridDim.y;
  int lin = blockIdx.y * gridDim.x + blockIdx.x;
  if ((nwg & 7) == 0) lin = (lin & 7) * (nwg >> 3) + (lin >> 3);
  const int bx = lin % gridDim.x, by = lin / gridDim.x;
  const int row0 = by * 128, col0 = bx * 128;

  const int c8sw = (l & 3) ^ (((l >> 5) & 1) << 1);
  const int lrow = l >> 2;
  const int chsw = lhi ^ (((l15 >> 3) & 1) << 1);
  const int rd_off = l15 * 32 + chsw * 8;

  const int sA0 = w * 2;
  const ushort* ga[2];
  const ushort* gb[2];
#pragma unroll
  for (int j = 0; j < 2; ++j) {
    int ar = min(row0 + (sA0 + j) * 16 + lrow, M - 1);
    ga[j] = A + (size_t)ar * K + c8sw * 8;
    gb[j] = Bt + (size_t)(col0 + (sA0 + j) * 16 + lrow) * K + c8sw * 8;
  }

#define STAGE(nb, kn)                                                     \
  do {                                                                    \
    GLOAD_LDS16(ga[0] + (kn), &lds[(nb)*BUF + (sA0 + 0) * 512]);          \
    GLOAD_LDS16(ga[1] + (kn), &lds[(nb)*BUF + (sA0 + 1) * 512]);          \
    GLOAD_LDS16(gb[0] + (kn), &lds[(nb)*BUF + 4096 + (sA0 + 0) * 512]);   \
    GLOAD_LDS16(gb[1] + (kn), &lds[(nb)*BUF + 4096 + (sA0 + 1) * 512]);   \
  } while (0)

  f32x4 acc[4][4] = {};

#define PHASE(cur, WAITLIT, STAGE_STMT)                                              \
  do {                                                                               \
    STAGE_STMT;                                                                      \
    asm volatile("s_waitcnt vmcnt(" WAITLIT ")" ::: "memory");                       \
    __builtin_amdgcn_s_barrier();                                                    \
    CFENCE;                                                                          \
    short8 af[4], bf[4];                                                             \
    const ushort* Ab = &lds[(cur)*BUF];                                              \
    const ushort* Bb = &lds[(cur)*BUF + 4096];                                       \
    _Pragma("unroll") for (int m = 0; m < 4; ++m)                                    \
        af[m] = *(const short8*)(Ab + (wm * 4 + m) * 512 + rd_off);                  \
    _Pragma("unroll") for (int n = 0; n < 4; ++n)                                    \
        bf[n] = *(const short8*)(Bb + (wn * 4 + n) * 512 + rd_off);                  \
    __builtin_amdgcn_s_setprio(1);                                                   \
    _Pragma("unroll") for (int m = 0; m < 4; ++m)                                    \
        _Pragma("unroll") for (int n = 0; n < 4; ++n)                                \
            acc[m][n] = __builtin_amdgcn_mfma_f32_16x16x32_bf16(                     \
                af[m], bf[n], acc[m][n], 0, 0, 0);                                   \
    __builtin_amdgcn_s_setprio(0);                                                   \
    CFENCE;                                                                          \
    __builtin_amdgcn_s_barrier();                                                    \
    CFENCE;                                                                          \
  } while (0)

  const int nt = K >> 5;
  STAGE(0, 0);
  int cur = 0;
  for (int t = 0; t < nt - 1; ++t) {
    const int kn = (t + 1) << 5;
    PHASE(cur, "4", STAGE(cur ^ 1, kn));
    cur ^= 1;
  }
  PHASE(cur, "0", );

#pragma unroll
  for (int mi = 0; mi < 4; ++mi) {
#pragma unroll
    for (int v = 0; v < 4; ++v) {
      int r = row0 + wm * 64 + mi * 16 + lhi * 4 + v;
      if (r < M) {
#pragma unroll
        for (int n = 0; n < 4; ++n) {
          int col = col0 + wn * 64 + n * 16 + l15;
          float val = fmaxf(acc[mi][n][v] + bias[col], 0.f);
          size_t idx = (size_t)r * Nout + col;
          if (BF16OUT)
            ((__hip_bfloat16*)C)[idx] = __float2bfloat16(val);
          else
            ((float*)C)[idx] = val;
        }
      }
    }
  }
#undef PHASE
#undef STAGE
}

// ---------------------------------------------------------------------------
// GEMM variant B (L2): 256x128, 8 waves, 2 buf (48 KiB), vmcnt(3), (512,4).
// ---------------------------------------------------------------------------
template <bool BF16OUT>
__global__ __launch_bounds__(512, 4) void gemm_p2(const ushort* __restrict__ A,
                                                  const ushort* __restrict__ Bt,
                                                  const float* __restrict__ bias,
                                                  void* __restrict__ C,
                                                  int M, int K, int Nout) {
  constexpr int BUF = 12288;
  extern __shared__ ushort lds[];
  const int tid = threadIdx.x;
  const int l = tid & 63, w = tid >> 6;
  const int wm = w >> 2, wn = w & 3;
  const int l15 = l & 15, lhi = l >> 4;

  int nwg = gridDim.x * gridDim.y;
  int lin = blockIdx.y * gridDim.x + blockIdx.x;
  if ((nwg & 7) == 0) lin = (lin & 7) * (nwg >> 3) + (lin >> 3);
  const int bx = lin % gridDim.x, by = lin / gridDim.x;
  const int row0 = by * 256, col0 = bx * 128;

  const int c8sw = (l & 3) ^ (((l >> 5) & 1) << 1);
  const int lrow = l >> 2;
  const int chsw = lhi ^ (((l15 >> 3) & 1) << 1);
  const int rd_off = l15 * 32 + chsw * 8;

  const int sA0 = w * 2;
  const int sB0 = w;
  const ushort* ga[2];
  const ushort* gb;
#pragma unroll
  for (int j = 0; j < 2; ++j) {
    int ar = min(row0 + (sA0 + j) * 16 + lrow, M - 1);
    ga[j] = A + (size_t)ar * K + c8sw * 8;
  }
  gb = Bt + (size_t)(col0 + sB0 * 16 + lrow) * K + c8sw * 8;

#define STAGE(nb, kn)                                               \
  do {                                                              \
    GLOAD_LDS16(ga[0] + (kn), &lds[(nb)*BUF + (sA0 + 0) * 512]);    \
    GLOAD_LDS16(ga[1] + (kn), &lds[(nb)*BUF + (sA0 + 1) * 512]);    \
    GLOAD_LDS16(gb + (kn), &lds[(nb)*BUF + 8192 + sB0 * 512]);      \
  } while (0)

  f32x4 acc[8][2] = {};

#define PHASE(cur, WAITLIT, STAGE_STMT)                                              \
  do {                                                                               \
    STAGE_STMT;                                                                      \
    asm volatile("s_waitcnt vmcnt(" WAITLIT ")" ::: "memory");                       \
    __builtin_amdgcn_s_barrier();                                                    \
    CFENCE;                                                                          \
    short8 af[8], bf[2];                                                             \
    const ushort* Ab = &lds[(cur)*BUF];                                              \
    const ushort* Bb = &lds[(cur)*BUF + 8192];                                       \
    _Pragma("unroll") for (int m = 0; m < 8; ++m)                                    \
        af[m] = *(const short8*)(Ab + (wm * 8 + m) * 512 + rd_off);                  \
    _Pragma("unroll") for (int n = 0; n < 2; ++n)                                    \
        bf[n] = *(const short8*)(Bb + (wn * 2 + n) * 512 + rd_off);                  \
    __builtin_amdgcn_s_setprio(1);                                                   \
    _Pragma("unroll") for (int m = 0; m < 8; ++m)                                    \
        _Pragma("unroll") for (int n = 0; n < 2; ++n)                                \
            acc[m][n] = __builtin_amdgcn_mfma_f32_16x16x32_bf16(                     \
                af[m], bf[n], acc[m][n], 0, 0, 0);                                   \
    __builtin_amdgcn_s_setprio(0);                                                   \
    CFENCE;                                                                          \
    __builtin_amdgcn_s_barrier();                                                    \
    CFENCE;                                                                          \
  } while (0)

  const int nt = K >> 5;
  STAGE(0, 0);
  int cur = 0;
  for (int t = 0; t < nt - 1; ++t) {
    const int kn = (t + 1) << 5;
    PHASE(cur, "3", STAGE(cur ^ 1, kn));
    cur ^= 1;
  }
  PHASE(cur, "0", );

#pragma unroll
  for (int mi = 0; mi < 8; ++mi) {
#pragma unroll
    for (int v = 0; v < 4; ++v) {
      int r = row0 + wm * 128 + mi * 16 + lhi * 4 + v;
      if (r < M) {
#pragma unroll
        for (int n = 0; n < 2; ++n) {
          int col = col0 + wn * 32 + n * 16 + l15;
          float val = fmaxf(acc[mi][n][v] + bias[col], 0.f);
          size_t idx = (size_t)r * Nout + col;
          if (BF16OUT)
            ((__hip_bfloat16*)C)[idx] = __float2bfloat16(val);
          else
            ((float*)C)[idx] = val;
        }
      }
    }
  }
#undef PHASE
#undef STAGE
}

// ---------------------------------------------------------------------------
// Row L2 normalize (eps 1e-12), f32 in, f32 out.
// ---------------------------------------------------------------------------
__global__ __launch_bounds__(256) void normalize_kernel(const float* __restrict__ h,
                                                        float* __restrict__ out,
                                                        int F) {
  int n = blockIdx.x;
  const float* row = h + (size_t)n * F;
  float ss = 0.f;
  for (int f = threadIdx.x; f < F; f += 256) {
    float v = row[f];
    ss += v * v;
  }
  float tot = block_reduce_sum_bcast(ss);
  float inv = 1.f / fmaxf(sqrtf(tot), 1e-12f);
  for (int f = threadIdx.x; f < F; f += 256) {
    out[(size_t)n * F + f] = row[f] * inv;
  }
}

// ---------------------------------------------------------------------------
extern "C" void kernel_launch(void* const* d_in, const int* in_sizes, int n_in,
                              void* d_out, int out_size, void* d_ws, size_t ws_size,
                              hipStream_t stream) {
  const float* x   = (const float*)d_in[0];
  const int*   ei  = (const int*)d_in[1];
  const float* W1  = (const float*)d_in[2];
  const float* W2  = (const float*)d_in[3];
  const float* W3  = (const float*)d_in[4];
  const float* a1s = (const float*)d_in[5];
  const float* a1d = (const float*)d_in[6];
  const float* a2s = (const float*)d_in[7];
  const float* a2d = (const float*)d_in[8];
  const float* a3s = (const float*)d_in[9];
  const float* a3d = (const float*)d_in[10];
  const float* b1  = (const float*)d_in[11];
  const float* b2  = (const float*)d_in[12];
  const float* b3  = (const float*)d_in[13];

  const int N = in_sizes[0] / 256;  // 10000
  const int E = in_sizes[1] / 2;    // 80000

  char* ws = (char*)d_ws;
  size_t off = 0;
  auto alloc = [&](size_t bytes) -> void* {
    void* p = ws + off;
    off += (bytes + 255) & ~(size_t)255;
    return p;
  };
  ushort* h    = (ushort*)alloc((size_t)N * 2048 * 2);
  ushort* hagg = (ushort*)alloc((size_t)N * 2048 * 2);
  float* hf32  = (float*)alloc((size_t)N * 1024 * 4);
  ushort* xb   = (ushort*)alloc((size_t)N * 256 * 2);
  __hip_bfloat16* Wt1 = (__hip_bfloat16*)alloc((size_t)2048 * 256 * 2);
  __hip_bfloat16* Wt2 = (__hip_bfloat16*)alloc((size_t)2048 * 2048 * 2);
  __hip_bfloat16* Wt3 = (__hip_bfloat16*)alloc((size_t)1024 * 2048 * 2);
  float* wa1s = (float*)alloc(256 * 4);
  float* wa1d = (float*)alloc(256 * 4);
  float* wa2s = (float*)alloc(2048 * 4);
  float* wa2d = (float*)alloc(2048 * 4);
  float* wa3s = (float*)alloc(2048 * 4);
  float* wa3d = (float*)alloc(2048 * 4);
  float* als   = (float*)alloc((size_t)N * 4);
  float* ald   = (float*)alloc((size_t)N * 4);
  int* counts  = (int*)alloc((size_t)N * 4);
  int* rowptr  = (int*)alloc((size_t)(N + 1) * 4);
  int* cursor  = (int*)alloc((size_t)N * 4);
  int* eidx    = (int*)alloc((size_t)E * 4);

  const int* srcp = ei;
  const int* dstp = ei + E;

  hipFuncSetAttribute((const void*)gemm_t128<true>,
                      hipFuncAttributeMaxDynamicSharedMemorySize, 32768);
  hipFuncSetAttribute((const void*)gemm_t128<false>,
                      hipFuncAttributeMaxDynamicSharedMemorySize, 32768);
  hipFuncSetAttribute((const void*)gemm_p2<true>,
                      hipFuncAttributeMaxDynamicSharedMemorySize, 49152);

  // CSR build (by dst)
  hipMemsetAsync(counts, 0, (size_t)N * 4, stream);
  count_kernel<<<(E + 255) / 256, 256, 0, stream>>>(dstp, counts, E);
  scan_kernel<<<1, 1024, 0, stream>>>(counts, rowptr, cursor, N);
  fill_kernel<<<(E + 255) / 256, 256, 0, stream>>>(srcp, dstp, cursor, eidx, E);

  // prep: bf16 casts, weight transposes, wa matvecs
  convert_f32_bf16<<<(N * 256 + 255) / 256, 256, 0, stream>>>(x, (__hip_bfloat16*)xb, N * 256);
  transpose_w<<<dim3(2048 / 32, 256 / 32), 256, 0, stream>>>(W1, Wt1, 256, 2048);
  transpose_w<<<dim3(2048 / 32, 2048 / 32), 256, 0, stream>>>(W2, Wt2, 2048, 2048);
  transpose_w<<<dim3(1024 / 32, 2048 / 32), 256, 0, stream>>>(W3, Wt3, 2048, 1024);
  matvec_wa<<<256, 256, 0, stream>>>(W1, a1s, a1d, wa1s, wa1d, 2048);
  matvec_wa<<<2048, 256, 0, stream>>>(W2, a2s, a2d, wa2s, wa2d, 2048);
  matvec_wa<<<2048, 256, 0, stream>>>(W3, a3s, a3d, wa3s, wa3d, 1024);

  dim3 blk(256);
  dim3 gblk(512);
  int mb128 = (N + 127) / 128;  // 79
  int mb256 = (N + 255) / 256;  // 40

  // layer 1: al on x (F=256), agg, GEMM 256->2048 (t128, grid 16x79)
  compute_al<1><<<N, blk, 0, stream>>>(xb, wa1s, wa1d, als, ald, 256);
  aggregate<1><<<N, blk, 0, stream>>>(xb, als, ald, rowptr, eidx, hagg, 256);
  gemm_t128<true><<<dim3(16, mb128), blk, 32768, stream>>>(hagg, (const ushort*)Wt1, b1, h, N, 256, 2048);

  // layer 2: al, agg, GEMM 2048->2048 (p2, grid 16x40)
  compute_al<8><<<N, blk, 0, stream>>>(h, wa2s, wa2d, als, ald, 2048);
  aggregate<8><<<N, blk, 0, stream>>>(h, als, ald, rowptr, eidx, hagg, 2048);
  gemm_p2<true><<<dim3(16, mb256), gblk, 49152, stream>>>(hagg, (const ushort*)Wt2, b2, h, N, 2048, 2048);

  // layer 3: al, agg, GEMM 2048->1024 f32 (t128, grid 8x79)
  compute_al<8><<<N, blk, 0, stream>>>(h, wa3s, wa3d, als, ald, 2048);
  aggregate<8><<<N, blk, 0, stream>>>(h, als, ald, rowptr, eidx, hagg, 2048);
  gemm_t128<false><<<dim3(8, mb128), blk, 32768, stream>>>(hagg, (const ushort*)Wt3, b3, hf32, N, 2048, 1024);

  normalize_kernel<<<N, blk, 0, stream>>>(hf32, (float*)d_out, 1024);
}

// Round 17
// 415.532 us; speedup vs baseline: 1.1326x; 1.0259x over previous
//
#include <hip/hip_runtime.h>
#include <hip/hip_bf16.h>
#include <math.h>

// ---------------------------------------------------------------------------
// 3-layer GAT forward. Round 17 = R16 (best, 426.3us) + low-risk traffic cuts:
//  - L3 GEMM writes bf16; normalize reads bf16 (saves 40MB).
//  - aggregate: single-pass softmax when deg+1 <= 256 (3-pass fallback kept).
//  - convert_f32_bf16 + compute_al<1> fused (one pass over x).
// GEMMs: L1/L3 = gemm_t128 (128x128, 4 blk/CU), L2 = gemm_p2 (256x128).
// ---------------------------------------------------------------------------

typedef __attribute__((ext_vector_type(8))) short short8;
typedef __attribute__((ext_vector_type(4))) float f32x4;

#define GLOAD_LDS16(g, l)                                            \
  __builtin_amdgcn_global_load_lds(                                  \
      (const __attribute__((address_space(1))) void*)(g),            \
      (__attribute__((address_space(3))) void*)(l), 16, 0, 0)

#define CFENCE asm volatile("" ::: "memory")

__device__ __forceinline__ float bf16_to_f32(ushort u) {
  return __uint_as_float(((unsigned int)u) << 16);
}

__device__ __forceinline__ float block_reduce_sum_bcast(float v) {
#pragma unroll
  for (int off = 32; off > 0; off >>= 1) v += __shfl_down(v, off, 64);
  __shared__ float tmp[4];
  __shared__ float res;
  int lane = threadIdx.x & 63, w = threadIdx.x >> 6;
  if (lane == 0) tmp[w] = v;
  __syncthreads();
  if (threadIdx.x == 0) res = tmp[0] + tmp[1] + tmp[2] + tmp[3];
  __syncthreads();
  float out = res;
  __syncthreads();
  return out;
}

__device__ __forceinline__ float block_reduce_max_bcast(float v) {
#pragma unroll
  for (int off = 32; off > 0; off >>= 1) v = fmaxf(v, __shfl_down(v, off, 64));
  __shared__ float tmpm[4];
  __shared__ float resm;
  int lane = threadIdx.x & 63, w = threadIdx.x >> 6;
  if (lane == 0) tmpm[w] = v;
  __syncthreads();
  if (threadIdx.x == 0) resm = fmaxf(fmaxf(tmpm[0], tmpm[1]), fmaxf(tmpm[2], tmpm[3]));
  __syncthreads();
  float out = resm;
  __syncthreads();
  return out;
}

// ---------------------------------------------------------------------------
// Fused: xb = bf16(x) AND als/ald = dot(bf16(x), wa).  One block per node,
// F=256, one element per thread.
// ---------------------------------------------------------------------------
__global__ __launch_bounds__(256) void convert_al1(const float* __restrict__ x,
                                                   ushort* __restrict__ xb,
                                                   const float* __restrict__ wa_s,
                                                   const float* __restrict__ wa_d,
                                                   float* __restrict__ als,
                                                   float* __restrict__ ald) {
  int n = blockIdx.x;
  int tid = threadIdx.x;
  float v = x[(size_t)n * 256 + tid];
  __hip_bfloat16 hv = __float2bfloat16(v);
  ushort bits = *(ushort*)&hv;
  xb[(size_t)n * 256 + tid] = bits;
  float f = bf16_to_f32(bits);
  float r1 = block_reduce_sum_bcast(f * wa_s[tid]);
  float r2 = block_reduce_sum_bcast(f * wa_d[tid]);
  if (tid == 0) {
    als[n] = r1;
    ald[n] = r2;
  }
}

// ---------------------------------------------------------------------------
// Transpose W [K][N] f32 -> Wt [N][K] bf16.  32x32 tiles, 256 threads.
// ---------------------------------------------------------------------------
__global__ __launch_bounds__(256) void transpose_w(const float* __restrict__ W,
                                                   __hip_bfloat16* __restrict__ Wt,
                                                   int K, int Nout) {
  __shared__ float t[32][33];
  int tx = threadIdx.x & 31, ty = threadIdx.x >> 5;  // 32 x 8
  int n0 = blockIdx.x * 32, k0 = blockIdx.y * 32;
#pragma unroll
  for (int i = 0; i < 4; ++i) {
    int k = k0 + ty + i * 8;
    t[ty + i * 8][tx] = W[(size_t)k * Nout + n0 + tx];
  }
  __syncthreads();
#pragma unroll
  for (int i = 0; i < 4; ++i) {
    int n = n0 + ty + i * 8;
    Wt[(size_t)n * K + k0 + tx] = __float2bfloat16(t[tx][ty + i * 8]);
  }
}

// ---------------------------------------------------------------------------
// wa_s[k] = sum_f W[k][f] * a_s[f];  wa_d likewise.  W row-major [K][F] f32.
// ---------------------------------------------------------------------------
__global__ __launch_bounds__(256) void matvec_wa(const float* __restrict__ W,
                                                 const float* __restrict__ a_s,
                                                 const float* __restrict__ a_d,
                                                 float* __restrict__ wa_s,
                                                 float* __restrict__ wa_d, int F) {
  int k = blockIdx.x;
  const float* row = W + (size_t)k * F;
  float s1 = 0.f, s2 = 0.f;
  for (int f = threadIdx.x; f < F; f += 256) {
    float w = row[f];
    s1 += w * a_s[f];
    s2 += w * a_d[f];
  }
  float r1 = block_reduce_sum_bcast(s1);
  float r2 = block_reduce_sum_bcast(s2);
  if (threadIdx.x == 0) {
    wa_s[k] = r1;
    wa_d[k] = r2;
  }
}

// ---------------------------------------------------------------------------
// als[n] = dot(H[n,:], wa_s); ald[n] = dot(H[n,:], wa_d).  H bf16 [N][F=2048].
// ---------------------------------------------------------------------------
__global__ __launch_bounds__(256) void compute_al8(const ushort* __restrict__ H,
                                                   const float* __restrict__ wa_s,
                                                   const float* __restrict__ wa_d,
                                                   float* __restrict__ als,
                                                   float* __restrict__ ald) {
  int n = blockIdx.x;
  const ushort* row = H + (size_t)n * 2048;
  float s1 = 0.f, s2 = 0.f;
  int base = threadIdx.x * 8;
  short8 v = *(const short8*)(row + base);
#pragma unroll
  for (int j = 0; j < 8; ++j) {
    float f = bf16_to_f32((ushort)v[j]);
    s1 += f * wa_s[base + j];
    s2 += f * wa_d[base + j];
  }
  float r1 = block_reduce_sum_bcast(s1);
  float r2 = block_reduce_sum_bcast(s2);
  if (threadIdx.x == 0) {
    als[n] = r1;
    ald[n] = r2;
  }
}

// ---------------------------------------------------------------------------
// CSR build (edge_index int32: [2][E], src then dst)
// ---------------------------------------------------------------------------
__global__ void count_kernel(const int* __restrict__ dst, int* __restrict__ counts, int E) {
  int i = blockIdx.x * blockDim.x + threadIdx.x;
  if (i < E) atomicAdd(&counts[dst[i]], 1);
}

__global__ __launch_bounds__(1024) void scan_kernel(const int* __restrict__ counts,
                                                    int* __restrict__ rowptr,
                                                    int* __restrict__ cursor, int Nn) {
  __shared__ int part[1024];
  int tid = threadIdx.x;
  int chunk = (Nn + 1023) / 1024;
  int base = tid * chunk;
  int s = 0;
  for (int i = 0; i < chunk; ++i) {
    int idx = base + i;
    if (idx < Nn) s += counts[idx];
  }
  part[tid] = s;
  __syncthreads();
  for (int off = 1; off < 1024; off <<= 1) {
    int v = 0;
    if (tid >= off) v = part[tid - off];
    __syncthreads();
    if (tid >= off) part[tid] += v;
    __syncthreads();
  }
  int run = (tid == 0) ? 0 : part[tid - 1];
  for (int i = 0; i < chunk; ++i) {
    int idx = base + i;
    if (idx < Nn) {
      rowptr[idx] = run;
      cursor[idx] = run;
      run += counts[idx];
    }
  }
  if (tid == 1023) rowptr[Nn] = part[1023];
}

__global__ void fill_kernel(const int* __restrict__ src, const int* __restrict__ dst,
                            int* __restrict__ cursor, int* __restrict__ eidx, int E) {
  int i = blockIdx.x * blockDim.x + threadIdx.x;
  if (i < E) {
    int pos = atomicAdd(&cursor[dst[i]], 1);
    eidx[pos] = src[i];
  }
}

// ---------------------------------------------------------------------------
// H_agg[n] = sum_e alpha_e * H_in[src_e]  (softmax attention, self-loop incl).
// Single-pass softmax when deg+1 <= 256 (e computed once, stored in LDS);
// 3-pass fallback otherwise.
// ---------------------------------------------------------------------------
template <int FPT>
__global__ __launch_bounds__(256) void aggregate(const ushort* __restrict__ H,
                                                 const float* __restrict__ als,
                                                 const float* __restrict__ ald,
                                                 const int* __restrict__ rowptr,
                                                 const int* __restrict__ eidx,
                                                 ushort* __restrict__ out, int F) {
  int n = blockIdx.x;
  int tid = threadIdx.x;
  int beg = rowptr[n], end = rowptr[n + 1];
  int deg = end - beg;
  int total = deg + 1;
  float aldn = ald[n];

  __shared__ float alpha_sh[256];
  __shared__ int src_sh[256];

  float acc[FPT];
#pragma unroll
  for (int i = 0; i < FPT; ++i) acc[i] = 0.f;

  if (total <= 256) {
    // -------- single-pass softmax --------
    int s = n;
    float e = -INFINITY;
    if (tid < total) {
      s = (tid < deg) ? eidx[beg + tid] : n;
      e = als[s] + aldn;
      e = (e > 0.f) ? e : 0.2f * e;
    }
    float m = block_reduce_max_bcast(e);
    float ex = (tid < total) ? expf(e - m) : 0.f;
    float denom = block_reduce_sum_bcast(ex) + 1e-16f;
    float inv_denom = 1.f / denom;
    alpha_sh[tid] = ex * inv_denom;
    src_sh[tid] = s;
    __syncthreads();
    for (int jj = 0; jj < total; ++jj) {
      float al = alpha_sh[jj];
      const ushort* row = H + (size_t)src_sh[jj] * F;
      if (FPT == 1) {
        acc[0] += al * bf16_to_f32(row[tid]);
      } else {
#pragma unroll
        for (int i = 0; i < FPT / 2; ++i) {
          unsigned int u = *(const unsigned int*)(row + tid * 2 + i * 512);
          acc[2 * i]     += al * __uint_as_float((u & 0xffffu) << 16);
          acc[2 * i + 1] += al * __uint_as_float(u & 0xffff0000u);
        }
      }
    }
  } else {
    // -------- 3-pass fallback (deg can exceed block size) --------
    float lm = -INFINITY;
    for (int j = tid; j < deg; j += 256) {
      int s = eidx[beg + j];
      float e = als[s] + aldn;
      e = (e > 0.f) ? e : 0.2f * e;
      lm = fmaxf(lm, e);
    }
    if (tid == 0) {
      float e = als[n] + aldn;
      e = (e > 0.f) ? e : 0.2f * e;
      lm = fmaxf(lm, e);
    }
    float m = block_reduce_max_bcast(lm);

    float ls = 0.f;
    for (int j = tid; j < deg; j += 256) {
      int s = eidx[beg + j];
      float e = als[s] + aldn;
      e = (e > 0.f) ? e : 0.2f * e;
      ls += expf(e - m);
    }
    if (tid == 0) {
      float e = als[n] + aldn;
      e = (e > 0.f) ? e : 0.2f * e;
      ls += expf(e - m);
    }
    float denom = block_reduce_sum_bcast(ls) + 1e-16f;
    float inv_denom = 1.f / denom;

    for (int c0 = 0; c0 < total; c0 += 256) {
      int j = c0 + tid;
      if (j < total) {
        int s = (j < deg) ? eidx[beg + j] : n;
        float e = als[s] + aldn;
        e = (e > 0.f) ? e : 0.2f * e;
        alpha_sh[tid] = expf(e - m) * inv_denom;
        src_sh[tid] = s;
      }
      __syncthreads();
      int cn = min(256, total - c0);
      for (int jj = 0; jj < cn; ++jj) {
        float al = alpha_sh[jj];
        const ushort* row = H + (size_t)src_sh[jj] * F;
        if (FPT == 1) {
          acc[0] += al * bf16_to_f32(row[tid]);
        } else {
#pragma unroll
          for (int i = 0; i < FPT / 2; ++i) {
            unsigned int u = *(const unsigned int*)(row + tid * 2 + i * 512);
            acc[2 * i]     += al * __uint_as_float((u & 0xffffu) << 16);
            acc[2 * i + 1] += al * __uint_as_float(u & 0xffff0000u);
          }
        }
      }
      __syncthreads();
    }
  }

#pragma unroll
  for (int i = 0; i < FPT; ++i) {
    int col = (FPT == 1) ? tid : (tid * 2 + (i >> 1) * 512 + (i & 1));
    __hip_bfloat16 hv = __float2bfloat16(acc[i]);
    out[(size_t)n * F + col] = *(ushort*)&hv;
  }
}

// ---------------------------------------------------------------------------
// GEMM variant A (L1/L3): 128x128, 4 waves, 2 buf (32 KiB), vmcnt(4), (256,4).
// ---------------------------------------------------------------------------
template <bool BF16OUT>
__global__ __launch_bounds__(256, 4) void gemm_t128(const ushort* __restrict__ A,
                                                    const ushort* __restrict__ Bt,
                                                    const float* __restrict__ bias,
                                                    void* __restrict__ C,
                                                    int M, int K, int Nout) {
  constexpr int BUF = 8192;
  extern __shared__ ushort lds[];
  const int tid = threadIdx.x;
  const int l = tid & 63, w = tid >> 6;
  const int wm = w >> 1, wn = w & 1;
  const int l15 = l & 15, lhi = l >> 4;

  int nwg = gridDim.x * gridDim.y;
  int lin = blockIdx.y * gridDim.x + blockIdx.x;
  if ((nwg & 7) == 0) lin = (lin & 7) * (nwg >> 3) + (lin >> 3);
  const int bx = lin % gridDim.x, by = lin / gridDim.x;
  const int row0 = by * 128, col0 = bx * 128;

  const int c8sw = (l & 3) ^ (((l >> 5) & 1) << 1);
  const int lrow = l >> 2;
  const int chsw = lhi ^ (((l15 >> 3) & 1) << 1);
  const int rd_off = l15 * 32 + chsw * 8;

  const int sA0 = w * 2;
  const ushort* ga[2];
  const ushort* gb[2];
#pragma unroll
  for (int j = 0; j < 2; ++j) {
    int ar = min(row0 + (sA0 + j) * 16 + lrow, M - 1);
    ga[j] = A + (size_t)ar * K + c8sw * 8;
    gb[j] = Bt + (size_t)(col0 + (sA0 + j) * 16 + lrow) * K + c8sw * 8;
  }

#define STAGE(nb, kn)                                                     \
  do {                                                                    \
    GLOAD_LDS16(ga[0] + (kn), &lds[(nb)*BUF + (sA0 + 0) * 512]);          \
    GLOAD_LDS16(ga[1] + (kn), &lds[(nb)*BUF + (sA0 + 1) * 512]);          \
    GLOAD_LDS16(gb[0] + (kn), &lds[(nb)*BUF + 4096 + (sA0 + 0) * 512]);   \
    GLOAD_LDS16(gb[1] + (kn), &lds[(nb)*BUF + 4096 + (sA0 + 1) * 512]);   \
  } while (0)

  f32x4 acc[4][4] = {};

#define PHASE(cur, WAITLIT, STAGE_STMT)                                              \
  do {                                                                               \
    STAGE_STMT;                                                                      \
    asm volatile("s_waitcnt vmcnt(" WAITLIT ")" ::: "memory");                       \
    __builtin_amdgcn_s_barrier();                                                    \
    CFENCE;                                                                          \
    short8 af[4], bf[4];                                                             \
    const ushort* Ab = &lds[(cur)*BUF];                                              \
    const ushort* Bb = &lds[(cur)*BUF + 4096];                                       \
    _Pragma("unroll") for (int m = 0; m < 4; ++m)                                    \
        af[m] = *(const short8*)(Ab + (wm * 4 + m) * 512 + rd_off);                  \
    _Pragma("unroll") for (int n = 0; n < 4; ++n)                                    \
        bf[n] = *(const short8*)(Bb + (wn * 4 + n) * 512 + rd_off);                  \
    __builtin_amdgcn_s_setprio(1);                                                   \
    _Pragma("unroll") for (int m = 0; m < 4; ++m)                                    \
        _Pragma("unroll") for (int n = 0; n < 4; ++n)                                \
            acc[m][n] = __builtin_amdgcn_mfma_f32_16x16x32_bf16(                     \
                af[m], bf[n], acc[m][n], 0, 0, 0);                                   \
    __builtin_amdgcn_s_setprio(0);                                                   \
    CFENCE;                                                                          \
    __builtin_amdgcn_s_barrier();                                                    \
    CFENCE;                                                                          \
  } while (0)

  const int nt = K >> 5;
  STAGE(0, 0);
  int cur = 0;
  for (int t = 0; t < nt - 1; ++t) {
    const int kn = (t + 1) << 5;
    PHASE(cur, "4", STAGE(cur ^ 1, kn));
    cur ^= 1;
  }
  PHASE(cur, "0", );

#pragma unroll
  for (int mi = 0; mi < 4; ++mi) {
#pragma unroll
    for (int v = 0; v < 4; ++v) {
      int r = row0 + wm * 64 + mi * 16 + lhi * 4 + v;
      if (r < M) {
#pragma unroll
        for (int n = 0; n < 4; ++n) {
          int col = col0 + wn * 64 + n * 16 + l15;
          float val = fmaxf(acc[mi][n][v] + bias[col], 0.f);
          size_t idx = (size_t)r * Nout + col;
          if (BF16OUT)
            ((__hip_bfloat16*)C)[idx] = __float2bfloat16(val);
          else
            ((float*)C)[idx] = val;
        }
      }
    }
  }
#undef PHASE
#undef STAGE
}

// ---------------------------------------------------------------------------
// GEMM variant B (L2): 256x128, 8 waves, 2 buf (48 KiB), vmcnt(3), (512,4).
// ---------------------------------------------------------------------------
template <bool BF16OUT>
__global__ __launch_bounds__(512, 4) void gemm_p2(const ushort* __restrict__ A,
                                                  const ushort* __restrict__ Bt,
                                                  const float* __restrict__ bias,
                                                  void* __restrict__ C,
                                                  int M, int K, int Nout) {
  constexpr int BUF = 12288;
  extern __shared__ ushort lds[];
  const int tid = threadIdx.x;
  const int l = tid & 63, w = tid >> 6;
  const int wm = w >> 2, wn = w & 3;
  const int l15 = l & 15, lhi = l >> 4;

  int nwg = gridDim.x * gridDim.y;
  int lin = blockIdx.y * gridDim.x + blockIdx.x;
  if ((nwg & 7) == 0) lin = (lin & 7) * (nwg >> 3) + (lin >> 3);
  const int bx = lin % gridDim.x, by = lin / gridDim.x;
  const int row0 = by * 256, col0 = bx * 128;

  const int c8sw = (l & 3) ^ (((l >> 5) & 1) << 1);
  const int lrow = l >> 2;
  const int chsw = lhi ^ (((l15 >> 3) & 1) << 1);
  const int rd_off = l15 * 32 + chsw * 8;

  const int sA0 = w * 2;
  const int sB0 = w;
  const ushort* ga[2];
  const ushort* gb;
#pragma unroll
  for (int j = 0; j < 2; ++j) {
    int ar = min(row0 + (sA0 + j) * 16 + lrow, M - 1);
    ga[j] = A + (size_t)ar * K + c8sw * 8;
  }
  gb = Bt + (size_t)(col0 + sB0 * 16 + lrow) * K + c8sw * 8;

#define STAGE(nb, kn)                                               \
  do {                                                              \
    GLOAD_LDS16(ga[0] + (kn), &lds[(nb)*BUF + (sA0 + 0) * 512]);    \
    GLOAD_LDS16(ga[1] + (kn), &lds[(nb)*BUF + (sA0 + 1) * 512]);    \
    GLOAD_LDS16(gb + (kn), &lds[(nb)*BUF + 8192 + sB0 * 512]);      \
  } while (0)

  f32x4 acc[8][2] = {};

#define PHASE(cur, WAITLIT, STAGE_STMT)                                              \
  do {                                                                               \
    STAGE_STMT;                                                                      \
    asm volatile("s_waitcnt vmcnt(" WAITLIT ")" ::: "memory");                       \
    __builtin_amdgcn_s_barrier();                                                    \
    CFENCE;                                                                          \
    short8 af[8], bf[2];                                                             \
    const ushort* Ab = &lds[(cur)*BUF];                                              \
    const ushort* Bb = &lds[(cur)*BUF + 8192];                                       \
    _Pragma("unroll") for (int m = 0; m < 8; ++m)                                    \
        af[m] = *(const short8*)(Ab + (wm * 8 + m) * 512 + rd_off);                  \
    _Pragma("unroll") for (int n = 0; n < 2; ++n)                                    \
        bf[n] = *(const short8*)(Bb + (wn * 2 + n) * 512 + rd_off);                  \
    __builtin_amdgcn_s_setprio(1);                                                   \
    _Pragma("unroll") for (int m = 0; m < 8; ++m)                                    \
        _Pragma("unroll") for (int n = 0; n < 2; ++n)                                \
            acc[m][n] = __builtin_amdgcn_mfma_f32_16x16x32_bf16(                     \
                af[m], bf[n], acc[m][n], 0, 0, 0);                                   \
    __builtin_amdgcn_s_setprio(0);                                                   \
    CFENCE;                                                                          \
    __builtin_amdgcn_s_barrier();                                                    \
    CFENCE;                                                                          \
  } while (0)

  const int nt = K >> 5;
  STAGE(0, 0);
  int cur = 0;
  for (int t = 0; t < nt - 1; ++t) {
    const int kn = (t + 1) << 5;
    PHASE(cur, "3", STAGE(cur ^ 1, kn));
    cur ^= 1;
  }
  PHASE(cur, "0", );

#pragma unroll
  for (int mi = 0; mi < 8; ++mi) {
#pragma unroll
    for (int v = 0; v < 4; ++v) {
      int r = row0 + wm * 128 + mi * 16 + lhi * 4 + v;
      if (r < M) {
#pragma unroll
        for (int n = 0; n < 2; ++n) {
          int col = col0 + wn * 32 + n * 16 + l15;
          float val = fmaxf(acc[mi][n][v] + bias[col], 0.f);
          size_t idx = (size_t)r * Nout + col;
          if (BF16OUT)
            ((__hip_bfloat16*)C)[idx] = __float2bfloat16(val);
          else
            ((float*)C)[idx] = val;
        }
      }
    }
  }
#undef PHASE
#undef STAGE
}

// ---------------------------------------------------------------------------
// Row L2 normalize from bf16 input (eps 1e-12), f32 out.
// ---------------------------------------------------------------------------
__global__ __launch_bounds__(256) void normalize_bf16(const ushort* __restrict__ h,
                                                      float* __restrict__ out,
                                                      int F) {
  int n = blockIdx.x;
  const ushort* row = h + (size_t)n * F;
  float ss = 0.f;
  float vals[4];  // F=1024, 4 per thread
#pragma unroll
  for (int i = 0; i < 4; ++i) {
    float v = bf16_to_f32(row[threadIdx.x + i * 256]);
    vals[i] = v;
    ss += v * v;
  }
  float tot = block_reduce_sum_bcast(ss);
  float inv = 1.f / fmaxf(sqrtf(tot), 1e-12f);
#pragma unroll
  for (int i = 0; i < 4; ++i) {
    out[(size_t)n * F + threadIdx.x + i * 256] = vals[i] * inv;
  }
}

// ---------------------------------------------------------------------------
extern "C" void kernel_launch(void* const* d_in, const int* in_sizes, int n_in,
                              void* d_out, int out_size, void* d_ws, size_t ws_size,
                              hipStream_t stream) {
  const float* x   = (const float*)d_in[0];
  const int*   ei  = (const int*)d_in[1];
  const float* W1  = (const float*)d_in[2];
  const float* W2  = (const float*)d_in[3];
  const float* W3  = (const float*)d_in[4];
  const float* a1s = (const float*)d_in[5];
  const float* a1d = (const float*)d_in[6];
  const float* a2s = (const float*)d_in[7];
  const float* a2d = (const float*)d_in[8];
  const float* a3s = (const float*)d_in[9];
  const float* a3d = (const float*)d_in[10];
  const float* b1  = (const float*)d_in[11];
  const float* b2  = (const float*)d_in[12];
  const float* b3  = (const float*)d_in[13];

  const int N = in_sizes[0] / 256;  // 10000
  const int E = in_sizes[1] / 2;    // 80000

  char* ws = (char*)d_ws;
  size_t off = 0;
  auto alloc = [&](size_t bytes) -> void* {
    void* p = ws + off;
    off += (bytes + 255) & ~(size_t)255;
    return p;
  };
  ushort* h    = (ushort*)alloc((size_t)N * 2048 * 2);
  ushort* hagg = (ushort*)alloc((size_t)N * 2048 * 2);
  ushort* xb   = (ushort*)alloc((size_t)N * 256 * 2);
  __hip_bfloat16* Wt1 = (__hip_bfloat16*)alloc((size_t)2048 * 256 * 2);
  __hip_bfloat16* Wt2 = (__hip_bfloat16*)alloc((size_t)2048 * 2048 * 2);
  __hip_bfloat16* Wt3 = (__hip_bfloat16*)alloc((size_t)1024 * 2048 * 2);
  float* wa1s = (float*)alloc(256 * 4);
  float* wa1d = (float*)alloc(256 * 4);
  float* wa2s = (float*)alloc(2048 * 4);
  float* wa2d = (float*)alloc(2048 * 4);
  float* wa3s = (float*)alloc(2048 * 4);
  float* wa3d = (float*)alloc(2048 * 4);
  float* als   = (float*)alloc((size_t)N * 4);
  float* ald   = (float*)alloc((size_t)N * 4);
  int* counts  = (int*)alloc((size_t)N * 4);
  int* rowptr  = (int*)alloc((size_t)(N + 1) * 4);
  int* cursor  = (int*)alloc((size_t)N * 4);
  int* eidx    = (int*)alloc((size_t)E * 4);

  const int* srcp = ei;
  const int* dstp = ei + E;

  hipFuncSetAttribute((const void*)gemm_t128<true>,
                      hipFuncAttributeMaxDynamicSharedMemorySize, 32768);
  hipFuncSetAttribute((const void*)gemm_p2<true>,
                      hipFuncAttributeMaxDynamicSharedMemorySize, 49152);

  // CSR build (by dst)
  hipMemsetAsync(counts, 0, (size_t)N * 4, stream);
  count_kernel<<<(E + 255) / 256, 256, 0, stream>>>(dstp, counts, E);
  scan_kernel<<<1, 1024, 0, stream>>>(counts, rowptr, cursor, N);
  fill_kernel<<<(E + 255) / 256, 256, 0, stream>>>(srcp, dstp, cursor, eidx, E);

  // prep: weight transposes, wa matvecs
  transpose_w<<<dim3(2048 / 32, 256 / 32), 256, 0, stream>>>(W1, Wt1, 256, 2048);
  transpose_w<<<dim3(2048 / 32, 2048 / 32), 256, 0, stream>>>(W2, Wt2, 2048, 2048);
  transpose_w<<<dim3(1024 / 32, 2048 / 32), 256, 0, stream>>>(W3, Wt3, 2048, 1024);
  matvec_wa<<<256, 256, 0, stream>>>(W1, a1s, a1d, wa1s, wa1d, 2048);
  matvec_wa<<<2048, 256, 0, stream>>>(W2, a2s, a2d, wa2s, wa2d, 2048);
  matvec_wa<<<2048, 256, 0, stream>>>(W3, a3s, a3d, wa3s, wa3d, 1024);

  dim3 blk(256);
  dim3 gblk(512);
  int mb128 = (N + 127) / 128;  // 79
  int mb256 = (N + 255) / 256;  // 40

  // layer 1: fused convert+al on x (F=256), agg, GEMM 256->2048 (t128)
  convert_al1<<<N, blk, 0, stream>>>(x, xb, wa1s, wa1d, als, ald);
  aggregate<1><<<N, blk, 0, stream>>>(xb, als, ald, rowptr, eidx, hagg, 256);
  gemm_t128<true><<<dim3(16, mb128), blk, 32768, stream>>>(hagg, (const ushort*)Wt1, b1, h, N, 256, 2048);

  // layer 2: al, agg, GEMM 2048->2048 (p2)
  compute_al8<<<N, blk, 0, stream>>>(h, wa2s, wa2d, als, ald);
  aggregate<8><<<N, blk, 0, stream>>>(h, als, ald, rowptr, eidx, hagg, 2048);
  gemm_p2<true><<<dim3(16, mb256), gblk, 49152, stream>>>(hagg, (const ushort*)Wt2, b2, h, N, 2048, 2048);

  // layer 3: al, agg, GEMM 2048->1024 bf16 out (t128)
  compute_al8<<<N, blk, 0, stream>>>(h, wa3s, wa3d, als, ald);
  aggregate<8><<<N, blk, 0, stream>>>(h, als, ald, rowptr, eidx, hagg, 2048);
  gemm_t128<true><<<dim3(8, mb128), blk, 32768, stream>>>(hagg, (const ushort*)Wt3, b3, h, N, 2048, 1024);

  // normalize from bf16 h -> f32 out
  normalize_bf16<<<N, blk, 0, stream>>>(h, (float*)d_out, 1024);
}

// Round 18
// 414.953 us; speedup vs baseline: 1.1342x; 1.0014x over previous
//
#include <hip/hip_runtime.h>
#include <hip/hip_bf16.h>
#include <math.h>

// ---------------------------------------------------------------------------
// 3-layer GAT forward. Round 18 = R17 (best, 415.5us) + aggregate<8> gather
// vectorized to short8 (16B/lane: 1 load/row/thread instead of 4; 16B store).
// Feature ownership: thread tid -> cols [tid*8, tid*8+8). Same arithmetic.
// ---------------------------------------------------------------------------

typedef __attribute__((ext_vector_type(8))) short short8;
typedef __attribute__((ext_vector_type(4))) float f32x4;

#define GLOAD_LDS16(g, l)                                            \
  __builtin_amdgcn_global_load_lds(                                  \
      (const __attribute__((address_space(1))) void*)(g),            \
      (__attribute__((address_space(3))) void*)(l), 16, 0, 0)

#define CFENCE asm volatile("" ::: "memory")

__device__ __forceinline__ float bf16_to_f32(ushort u) {
  return __uint_as_float(((unsigned int)u) << 16);
}

__device__ __forceinline__ ushort f32_to_bf16_bits(float f) {
  __hip_bfloat16 hv = __float2bfloat16(f);
  return *(ushort*)&hv;
}

__device__ __forceinline__ float block_reduce_sum_bcast(float v) {
#pragma unroll
  for (int off = 32; off > 0; off >>= 1) v += __shfl_down(v, off, 64);
  __shared__ float tmp[4];
  __shared__ float res;
  int lane = threadIdx.x & 63, w = threadIdx.x >> 6;
  if (lane == 0) tmp[w] = v;
  __syncthreads();
  if (threadIdx.x == 0) res = tmp[0] + tmp[1] + tmp[2] + tmp[3];
  __syncthreads();
  float out = res;
  __syncthreads();
  return out;
}

__device__ __forceinline__ float block_reduce_max_bcast(float v) {
#pragma unroll
  for (int off = 32; off > 0; off >>= 1) v = fmaxf(v, __shfl_down(v, off, 64));
  __shared__ float tmpm[4];
  __shared__ float resm;
  int lane = threadIdx.x & 63, w = threadIdx.x >> 6;
  if (lane == 0) tmpm[w] = v;
  __syncthreads();
  if (threadIdx.x == 0) resm = fmaxf(fmaxf(tmpm[0], tmpm[1]), fmaxf(tmpm[2], tmpm[3]));
  __syncthreads();
  float out = resm;
  __syncthreads();
  return out;
}

// ---------------------------------------------------------------------------
// Fused: xb = bf16(x) AND als/ald = dot(bf16(x), wa).  One block per node.
// ---------------------------------------------------------------------------
__global__ __launch_bounds__(256) void convert_al1(const float* __restrict__ x,
                                                   ushort* __restrict__ xb,
                                                   const float* __restrict__ wa_s,
                                                   const float* __restrict__ wa_d,
                                                   float* __restrict__ als,
                                                   float* __restrict__ ald) {
  int n = blockIdx.x;
  int tid = threadIdx.x;
  float v = x[(size_t)n * 256 + tid];
  ushort bits = f32_to_bf16_bits(v);
  xb[(size_t)n * 256 + tid] = bits;
  float f = bf16_to_f32(bits);
  float r1 = block_reduce_sum_bcast(f * wa_s[tid]);
  float r2 = block_reduce_sum_bcast(f * wa_d[tid]);
  if (tid == 0) {
    als[n] = r1;
    ald[n] = r2;
  }
}

// ---------------------------------------------------------------------------
// Transpose W [K][N] f32 -> Wt [N][K] bf16.  32x32 tiles, 256 threads.
// ---------------------------------------------------------------------------
__global__ __launch_bounds__(256) void transpose_w(const float* __restrict__ W,
                                                   __hip_bfloat16* __restrict__ Wt,
                                                   int K, int Nout) {
  __shared__ float t[32][33];
  int tx = threadIdx.x & 31, ty = threadIdx.x >> 5;  // 32 x 8
  int n0 = blockIdx.x * 32, k0 = blockIdx.y * 32;
#pragma unroll
  for (int i = 0; i < 4; ++i) {
    int k = k0 + ty + i * 8;
    t[ty + i * 8][tx] = W[(size_t)k * Nout + n0 + tx];
  }
  __syncthreads();
#pragma unroll
  for (int i = 0; i < 4; ++i) {
    int n = n0 + ty + i * 8;
    Wt[(size_t)n * K + k0 + tx] = __float2bfloat16(t[tx][ty + i * 8]);
  }
}

// ---------------------------------------------------------------------------
// wa_s[k] = sum_f W[k][f] * a_s[f];  wa_d likewise.  W row-major [K][F] f32.
// ---------------------------------------------------------------------------
__global__ __launch_bounds__(256) void matvec_wa(const float* __restrict__ W,
                                                 const float* __restrict__ a_s,
                                                 const float* __restrict__ a_d,
                                                 float* __restrict__ wa_s,
                                                 float* __restrict__ wa_d, int F) {
  int k = blockIdx.x;
  const float* row = W + (size_t)k * F;
  float s1 = 0.f, s2 = 0.f;
  for (int f = threadIdx.x; f < F; f += 256) {
    float w = row[f];
    s1 += w * a_s[f];
    s2 += w * a_d[f];
  }
  float r1 = block_reduce_sum_bcast(s1);
  float r2 = block_reduce_sum_bcast(s2);
  if (threadIdx.x == 0) {
    wa_s[k] = r1;
    wa_d[k] = r2;
  }
}

// ---------------------------------------------------------------------------
// als[n] = dot(H[n,:], wa_s); ald[n] = dot(H[n,:], wa_d).  H bf16 [N][2048].
// ---------------------------------------------------------------------------
__global__ __launch_bounds__(256) void compute_al8(const ushort* __restrict__ H,
                                                   const float* __restrict__ wa_s,
                                                   const float* __restrict__ wa_d,
                                                   float* __restrict__ als,
                                                   float* __restrict__ ald) {
  int n = blockIdx.x;
  const ushort* row = H + (size_t)n * 2048;
  float s1 = 0.f, s2 = 0.f;
  int base = threadIdx.x * 8;
  short8 v = *(const short8*)(row + base);
#pragma unroll
  for (int j = 0; j < 8; ++j) {
    float f = bf16_to_f32((ushort)v[j]);
    s1 += f * wa_s[base + j];
    s2 += f * wa_d[base + j];
  }
  float r1 = block_reduce_sum_bcast(s1);
  float r2 = block_reduce_sum_bcast(s2);
  if (threadIdx.x == 0) {
    als[n] = r1;
    ald[n] = r2;
  }
}

// ---------------------------------------------------------------------------
// CSR build (edge_index int32: [2][E], src then dst)
// ---------------------------------------------------------------------------
__global__ void count_kernel(const int* __restrict__ dst, int* __restrict__ counts, int E) {
  int i = blockIdx.x * blockDim.x + threadIdx.x;
  if (i < E) atomicAdd(&counts[dst[i]], 1);
}

__global__ __launch_bounds__(1024) void scan_kernel(const int* __restrict__ counts,
                                                    int* __restrict__ rowptr,
                                                    int* __restrict__ cursor, int Nn) {
  __shared__ int part[1024];
  int tid = threadIdx.x;
  int chunk = (Nn + 1023) / 1024;
  int base = tid * chunk;
  int s = 0;
  for (int i = 0; i < chunk; ++i) {
    int idx = base + i;
    if (idx < Nn) s += counts[idx];
  }
  part[tid] = s;
  __syncthreads();
  for (int off = 1; off < 1024; off <<= 1) {
    int v = 0;
    if (tid >= off) v = part[tid - off];
    __syncthreads();
    if (tid >= off) part[tid] += v;
    __syncthreads();
  }
  int run = (tid == 0) ? 0 : part[tid - 1];
  for (int i = 0; i < chunk; ++i) {
    int idx = base + i;
    if (idx < Nn) {
      rowptr[idx] = run;
      cursor[idx] = run;
      run += counts[idx];
    }
  }
  if (tid == 1023) rowptr[Nn] = part[1023];
}

__global__ void fill_kernel(const int* __restrict__ src, const int* __restrict__ dst,
                            int* __restrict__ cursor, int* __restrict__ eidx, int E) {
  int i = blockIdx.x * blockDim.x + threadIdx.x;
  if (i < E) {
    int pos = atomicAdd(&cursor[dst[i]], 1);
    eidx[pos] = src[i];
  }
}

// ---------------------------------------------------------------------------
// aggregate, F=2048: thread owns cols [tid*8, tid*8+8); gather = one short8
// (16B) load per neighbor row; store = one short8. Single-pass softmax when
// deg+1 <= 256; 3-pass fallback.
// ---------------------------------------------------------------------------
__global__ __launch_bounds__(256) void aggregate8(const ushort* __restrict__ H,
                                                  const float* __restrict__ als,
                                                  const float* __restrict__ ald,
                                                  const int* __restrict__ rowptr,
                                                  const int* __restrict__ eidx,
                                                  ushort* __restrict__ out) {
  const int F = 2048;
  int n = blockIdx.x;
  int tid = threadIdx.x;
  int beg = rowptr[n], end = rowptr[n + 1];
  int deg = end - beg;
  int total = deg + 1;
  float aldn = ald[n];

  __shared__ float alpha_sh[256];
  __shared__ int src_sh[256];

  float acc[8];
#pragma unroll
  for (int i = 0; i < 8; ++i) acc[i] = 0.f;
  const int base = tid * 8;

  if (total <= 256) {
    int s = n;
    float e = -INFINITY;
    if (tid < total) {
      s = (tid < deg) ? eidx[beg + tid] : n;
      e = als[s] + aldn;
      e = (e > 0.f) ? e : 0.2f * e;
    }
    float m = block_reduce_max_bcast(e);
    float ex = (tid < total) ? expf(e - m) : 0.f;
    float denom = block_reduce_sum_bcast(ex) + 1e-16f;
    float inv_denom = 1.f / denom;
    alpha_sh[tid] = ex * inv_denom;
    src_sh[tid] = s;
    __syncthreads();
    for (int jj = 0; jj < total; ++jj) {
      float al = alpha_sh[jj];
      short8 v = *(const short8*)(H + (size_t)src_sh[jj] * F + base);
#pragma unroll
      for (int i = 0; i < 8; ++i) acc[i] += al * bf16_to_f32((ushort)v[i]);
    }
  } else {
    float lm = -INFINITY;
    for (int j = tid; j < deg; j += 256) {
      int s = eidx[beg + j];
      float e = als[s] + aldn;
      e = (e > 0.f) ? e : 0.2f * e;
      lm = fmaxf(lm, e);
    }
    if (tid == 0) {
      float e = als[n] + aldn;
      e = (e > 0.f) ? e : 0.2f * e;
      lm = fmaxf(lm, e);
    }
    float m = block_reduce_max_bcast(lm);

    float ls = 0.f;
    for (int j = tid; j < deg; j += 256) {
      int s = eidx[beg + j];
      float e = als[s] + aldn;
      e = (e > 0.f) ? e : 0.2f * e;
      ls += expf(e - m);
    }
    if (tid == 0) {
      float e = als[n] + aldn;
      e = (e > 0.f) ? e : 0.2f * e;
      ls += expf(e - m);
    }
    float denom = block_reduce_sum_bcast(ls) + 1e-16f;
    float inv_denom = 1.f / denom;

    for (int c0 = 0; c0 < total; c0 += 256) {
      int j = c0 + tid;
      if (j < total) {
        int s = (j < deg) ? eidx[beg + j] : n;
        float e = als[s] + aldn;
        e = (e > 0.f) ? e : 0.2f * e;
        alpha_sh[tid] = expf(e - m) * inv_denom;
        src_sh[tid] = s;
      }
      __syncthreads();
      int cn = min(256, total - c0);
      for (int jj = 0; jj < cn; ++jj) {
        float al = alpha_sh[jj];
        short8 v = *(const short8*)(H + (size_t)src_sh[jj] * F + base);
#pragma unroll
        for (int i = 0; i < 8; ++i) acc[i] += al * bf16_to_f32((ushort)v[i]);
      }
      __syncthreads();
    }
  }

  short8 sv;
#pragma unroll
  for (int i = 0; i < 8; ++i) sv[i] = (short)f32_to_bf16_bits(acc[i]);
  *(short8*)(out + (size_t)n * F + base) = sv;
}

// ---------------------------------------------------------------------------
// aggregate, F=256 (layer 1): one col per thread (small, keep simple).
// ---------------------------------------------------------------------------
__global__ __launch_bounds__(256) void aggregate1(const ushort* __restrict__ H,
                                                  const float* __restrict__ als,
                                                  const float* __restrict__ ald,
                                                  const int* __restrict__ rowptr,
                                                  const int* __restrict__ eidx,
                                                  ushort* __restrict__ out) {
  const int F = 256;
  int n = blockIdx.x;
  int tid = threadIdx.x;
  int beg = rowptr[n], end = rowptr[n + 1];
  int deg = end - beg;
  int total = deg + 1;
  float aldn = ald[n];

  __shared__ float alpha_sh[256];
  __shared__ int src_sh[256];

  float acc = 0.f;

  if (total <= 256) {
    int s = n;
    float e = -INFINITY;
    if (tid < total) {
      s = (tid < deg) ? eidx[beg + tid] : n;
      e = als[s] + aldn;
      e = (e > 0.f) ? e : 0.2f * e;
    }
    float m = block_reduce_max_bcast(e);
    float ex = (tid < total) ? expf(e - m) : 0.f;
    float denom = block_reduce_sum_bcast(ex) + 1e-16f;
    float inv_denom = 1.f / denom;
    alpha_sh[tid] = ex * inv_denom;
    src_sh[tid] = s;
    __syncthreads();
    for (int jj = 0; jj < total; ++jj) {
      acc += alpha_sh[jj] * bf16_to_f32(H[(size_t)src_sh[jj] * F + tid]);
    }
  } else {
    float lm = -INFINITY;
    for (int j = tid; j < deg; j += 256) {
      int s = eidx[beg + j];
      float e = als[s] + aldn;
      e = (e > 0.f) ? e : 0.2f * e;
      lm = fmaxf(lm, e);
    }
    if (tid == 0) {
      float e = als[n] + aldn;
      e = (e > 0.f) ? e : 0.2f * e;
      lm = fmaxf(lm, e);
    }
    float m = block_reduce_max_bcast(lm);
    float ls = 0.f;
    for (int j = tid; j < deg; j += 256) {
      int s = eidx[beg + j];
      float e = als[s] + aldn;
      e = (e > 0.f) ? e : 0.2f * e;
      ls += expf(e - m);
    }
    if (tid == 0) {
      float e = als[n] + aldn;
      e = (e > 0.f) ? e : 0.2f * e;
      ls += expf(e - m);
    }
    float denom = block_reduce_sum_bcast(ls) + 1e-16f;
    float inv_denom = 1.f / denom;
    for (int c0 = 0; c0 < total; c0 += 256) {
      int j = c0 + tid;
      if (j < total) {
        int s = (j < deg) ? eidx[beg + j] : n;
        float e = als[s] + aldn;
        e = (e > 0.f) ? e : 0.2f * e;
        alpha_sh[tid] = expf(e - m) * inv_denom;
        src_sh[tid] = s;
      }
      __syncthreads();
      int cn = min(256, total - c0);
      for (int jj = 0; jj < cn; ++jj) {
        acc += alpha_sh[jj] * bf16_to_f32(H[(size_t)src_sh[jj] * F + tid]);
      }
      __syncthreads();
    }
  }

  out[(size_t)n * F + tid] = f32_to_bf16_bits(acc);
}

// ---------------------------------------------------------------------------
// GEMM variant A (L1/L3): 128x128, 4 waves, 2 buf (32 KiB), vmcnt(4), (256,4).
// ---------------------------------------------------------------------------
template <bool BF16OUT>
__global__ __launch_bounds__(256, 4) void gemm_t128(const ushort* __restrict__ A,
                                                    const ushort* __restrict__ Bt,
                                                    const float* __restrict__ bias,
                                                    void* __restrict__ C,
                                                    int M, int K, int Nout) {
  constexpr int BUF = 8192;
  extern __shared__ ushort lds[];
  const int tid = threadIdx.x;
  const int l = tid & 63, w = tid >> 6;
  const int wm = w >> 1, wn = w & 1;
  const int l15 = l & 15, lhi = l >> 4;

  int nwg = gridDim.x * gridDim.y;
  int lin = blockIdx.y * gridDim.x + blockIdx.x;
  if ((nwg & 7) == 0) lin = (lin & 7) * (nwg >> 3) + (lin >> 3);
  const int bx = lin % gridDim.x, by = lin / gridDim.x;
  const int row0 = by * 128, col0 = bx * 128;

  const int c8sw = (l & 3) ^ (((l >> 5) & 1) << 1);
  const int lrow = l >> 2;
  const int chsw = lhi ^ (((l15 >> 3) & 1) << 1);
  const int rd_off = l15 * 32 + chsw * 8;

  const int sA0 = w * 2;
  const ushort* ga[2];
  const ushort* gb[2];
#pragma unroll
  for (int j = 0; j < 2; ++j) {
    int ar = min(row0 + (sA0 + j) * 16 + lrow, M - 1);
    ga[j] = A + (size_t)ar * K + c8sw * 8;
    gb[j] = Bt + (size_t)(col0 + (sA0 + j) * 16 + lrow) * K + c8sw * 8;
  }

#define STAGE(nb, kn)                                                     \
  do {                                                                    \
    GLOAD_LDS16(ga[0] + (kn), &lds[(nb)*BUF + (sA0 + 0) * 512]);          \
    GLOAD_LDS16(ga[1] + (kn), &lds[(nb)*BUF + (sA0 + 1) * 512]);          \
    GLOAD_LDS16(gb[0] + (kn), &lds[(nb)*BUF + 4096 + (sA0 + 0) * 512]);   \
    GLOAD_LDS16(gb[1] + (kn), &lds[(nb)*BUF + 4096 + (sA0 + 1) * 512]);   \
  } while (0)

  f32x4 acc[4][4] = {};

#define PHASE(cur, WAITLIT, STAGE_STMT)                                              \
  do {                                                                               \
    STAGE_STMT;                                                                      \
    asm volatile("s_waitcnt vmcnt(" WAITLIT ")" ::: "memory");                       \
    __builtin_amdgcn_s_barrier();                                                    \
    CFENCE;                                                                          \
    short8 af[4], bf[4];                                                             \
    const ushort* Ab = &lds[(cur)*BUF];                                              \
    const ushort* Bb = &lds[(cur)*BUF + 4096];                                       \
    _Pragma("unroll") for (int m = 0; m < 4; ++m)                                    \
        af[m] = *(const short8*)(Ab + (wm * 4 + m) * 512 + rd_off);                  \
    _Pragma("unroll") for (int n = 0; n < 4; ++n)                                    \
        bf[n] = *(const short8*)(Bb + (wn * 4 + n) * 512 + rd_off);                  \
    __builtin_amdgcn_s_setprio(1);                                                   \
    _Pragma("unroll") for (int m = 0; m < 4; ++m)                                    \
        _Pragma("unroll") for (int n = 0; n < 4; ++n)                                \
            acc[m][n] = __builtin_amdgcn_mfma_f32_16x16x32_bf16(                     \
                af[m], bf[n], acc[m][n], 0, 0, 0);                                   \
    __builtin_amdgcn_s_setprio(0);                                                   \
    CFENCE;                                                                          \
    __builtin_amdgcn_s_barrier();                                                    \
    CFENCE;                                                                          \
  } while (0)

  const int nt = K >> 5;
  STAGE(0, 0);
  int cur = 0;
  for (int t = 0; t < nt - 1; ++t) {
    const int kn = (t + 1) << 5;
    PHASE(cur, "4", STAGE(cur ^ 1, kn));
    cur ^= 1;
  }
  PHASE(cur, "0", );

#pragma unroll
  for (int mi = 0; mi < 4; ++mi) {
#pragma unroll
    for (int v = 0; v < 4; ++v) {
      int r = row0 + wm * 64 + mi * 16 + lhi * 4 + v;
      if (r < M) {
#pragma unroll
        for (int n = 0; n < 4; ++n) {
          int col = col0 + wn * 64 + n * 16 + l15;
          float val = fmaxf(acc[mi][n][v] + bias[col], 0.f);
          size_t idx = (size_t)r * Nout + col;
          if (BF16OUT)
            ((__hip_bfloat16*)C)[idx] = __float2bfloat16(val);
          else
            ((float*)C)[idx] = val;
        }
      }
    }
  }
#undef PHASE
#undef STAGE
}

// ---------------------------------------------------------------------------
// GEMM variant B (L2): 256x128, 8 waves, 2 buf (48 KiB), vmcnt(3), (512,4).
// ---------------------------------------------------------------------------
template <bool BF16OUT>
__global__ __launch_bounds__(512, 4) void gemm_p2(const ushort* __restrict__ A,
                                                  const ushort* __restrict__ Bt,
                                                  const float* __restrict__ bias,
                                                  void* __restrict__ C,
                                                  int M, int K, int Nout) {
  constexpr int BUF = 12288;
  extern __shared__ ushort lds[];
  const int tid = threadIdx.x;
  const int l = tid & 63, w = tid >> 6;
  const int wm = w >> 2, wn = w & 3;
  const int l15 = l & 15, lhi = l >> 4;

  int nwg = gridDim.x * gridDim.y;
  int lin = blockIdx.y * gridDim.x + blockIdx.x;
  if ((nwg & 7) == 0) lin = (lin & 7) * (nwg >> 3) + (lin >> 3);
  const int bx = lin % gridDim.x, by = lin / gridDim.x;
  const int row0 = by * 256, col0 = bx * 128;

  const int c8sw = (l & 3) ^ (((l >> 5) & 1) << 1);
  const int lrow = l >> 2;
  const int chsw = lhi ^ (((l15 >> 3) & 1) << 1);
  const int rd_off = l15 * 32 + chsw * 8;

  const int sA0 = w * 2;
  const int sB0 = w;
  const ushort* ga[2];
  const ushort* gb;
#pragma unroll
  for (int j = 0; j < 2; ++j) {
    int ar = min(row0 + (sA0 + j) * 16 + lrow, M - 1);
    ga[j] = A + (size_t)ar * K + c8sw * 8;
  }
  gb = Bt + (size_t)(col0 + sB0 * 16 + lrow) * K + c8sw * 8;

#define STAGE(nb, kn)                                               \
  do {                                                              \
    GLOAD_LDS16(ga[0] + (kn), &lds[(nb)*BUF + (sA0 + 0) * 512]);    \
    GLOAD_LDS16(ga[1] + (kn), &lds[(nb)*BUF + (sA0 + 1) * 512]);    \
    GLOAD_LDS16(gb + (kn), &lds[(nb)*BUF + 8192 + sB0 * 512]);      \
  } while (0)

  f32x4 acc[8][2] = {};

#define PHASE(cur, WAITLIT, STAGE_STMT)                                              \
  do {                                                                               \
    STAGE_STMT;                                                                      \
    asm volatile("s_waitcnt vmcnt(" WAITLIT ")" ::: "memory");                       \
    __builtin_amdgcn_s_barrier();                                                    \
    CFENCE;                                                                          \
    short8 af[8], bf[2];                                                             \
    const ushort* Ab = &lds[(cur)*BUF];                                              \
    const ushort* Bb = &lds[(cur)*BUF + 8192];                                       \
    _Pragma("unroll") for (int m = 0; m < 8; ++m)                                    \
        af[m] = *(const short8*)(Ab + (wm * 8 + m) * 512 + rd_off);                  \
    _Pragma("unroll") for (int n = 0; n < 2; ++n)                                    \
        bf[n] = *(const short8*)(Bb + (wn * 2 + n) * 512 + rd_off);                  \
    __builtin_amdgcn_s_setprio(1);                                                   \
    _Pragma("unroll") for (int m = 0; m < 8; ++m)                                    \
        _Pragma("unroll") for (int n = 0; n < 2; ++n)                                \
            acc[m][n] = __builtin_amdgcn_mfma_f32_16x16x32_bf16(                     \
                af[m], bf[n], acc[m][n], 0, 0, 0);                                   \
    __builtin_amdgcn_s_setprio(0);                                                   \
    CFENCE;                                                                          \
    __builtin_amdgcn_s_barrier();                                                    \
    CFENCE;                                                                          \
  } while (0)

  const int nt = K >> 5;
  STAGE(0, 0);
  int cur = 0;
  for (int t = 0; t < nt - 1; ++t) {
    const int kn = (t + 1) << 5;
    PHASE(cur, "3", STAGE(cur ^ 1, kn));
    cur ^= 1;
  }
  PHASE(cur, "0", );

#pragma unroll
  for (int mi = 0; mi < 8; ++mi) {
#pragma unroll
    for (int v = 0; v < 4; ++v) {
      int r = row0 + wm * 128 + mi * 16 + lhi * 4 + v;
      if (r < M) {
#pragma unroll
        for (int n = 0; n < 2; ++n) {
          int col = col0 + wn * 32 + n * 16 + l15;
          float val = fmaxf(acc[mi][n][v] + bias[col], 0.f);
          size_t idx = (size_t)r * Nout + col;
          if (BF16OUT)
            ((__hip_bfloat16*)C)[idx] = __float2bfloat16(val);
          else
            ((float*)C)[idx] = val;
        }
      }
    }
  }
#undef PHASE
#undef STAGE
}

// ---------------------------------------------------------------------------
// Row L2 normalize from bf16 input (eps 1e-12), f32 out.
// ---------------------------------------------------------------------------
__global__ __launch_bounds__(256) void normalize_bf16(const ushort* __restrict__ h,
                                                      float* __restrict__ out,
                                                      int F) {
  int n = blockIdx.x;
  const ushort* row = h + (size_t)n * F;
  float ss = 0.f;
  float vals[4];  // F=1024, 4 per thread
#pragma unroll
  for (int i = 0; i < 4; ++i) {
    float v = bf16_to_f32(row[threadIdx.x + i * 256]);
    vals[i] = v;
    ss += v * v;
  }
  float tot = block_reduce_sum_bcast(ss);
  float inv = 1.f / fmaxf(sqrtf(tot), 1e-12f);
#pragma unroll
  for (int i = 0; i < 4; ++i) {
    out[(size_t)n * F + threadIdx.x + i * 256] = vals[i] * inv;
  }
}

// ---------------------------------------------------------------------------
extern "C" void kernel_launch(void* const* d_in, const int* in_sizes, int n_in,
                              void* d_out, int out_size, void* d_ws, size_t ws_size,
                              hipStream_t stream) {
  const float* x   = (const float*)d_in[0];
  const int*   ei  = (const int*)d_in[1];
  const float* W1  = (const float*)d_in[2];
  const float* W2  = (const float*)d_in[3];
  const float* W3  = (const float*)d_in[4];
  const float* a1s = (const float*)d_in[5];
  const float* a1d = (const float*)d_in[6];
  const float* a2s = (const float*)d_in[7];
  const float* a2d = (const float*)d_in[8];
  const float* a3s = (const float*)d_in[9];
  const float* a3d = (const float*)d_in[10];
  const float* b1  = (const float*)d_in[11];
  const float* b2  = (const float*)d_in[12];
  const float* b3  = (const float*)d_in[13];

  const int N = in_sizes[0] / 256;  // 10000
  const int E = in_sizes[1] / 2;    // 80000

  char* ws = (char*)d_ws;
  size_t off = 0;
  auto alloc = [&](size_t bytes) -> void* {
    void* p = ws + off;
    off += (bytes + 255) & ~(size_t)255;
    return p;
  };
  ushort* h    = (ushort*)alloc((size_t)N * 2048 * 2);
  ushort* hagg = (ushort*)alloc((size_t)N * 2048 * 2);
  ushort* xb   = (ushort*)alloc((size_t)N * 256 * 2);
  __hip_bfloat16* Wt1 = (__hip_bfloat16*)alloc((size_t)2048 * 256 * 2);
  __hip_bfloat16* Wt2 = (__hip_bfloat16*)alloc((size_t)2048 * 2048 * 2);
  __hip_bfloat16* Wt3 = (__hip_bfloat16*)alloc((size_t)1024 * 2048 * 2);
  float* wa1s = (float*)alloc(256 * 4);
  float* wa1d = (float*)alloc(256 * 4);
  float* wa2s = (float*)alloc(2048 * 4);
  float* wa2d = (float*)alloc(2048 * 4);
  float* wa3s = (float*)alloc(2048 * 4);
  float* wa3d = (float*)alloc(2048 * 4);
  float* als   = (float*)alloc((size_t)N * 4);
  float* ald   = (float*)alloc((size_t)N * 4);
  int* counts  = (int*)alloc((size_t)N * 4);
  int* rowptr  = (int*)alloc((size_t)(N + 1) * 4);
  int* cursor  = (int*)alloc((size_t)N * 4);
  int* eidx    = (int*)alloc((size_t)E * 4);

  const int* srcp = ei;
  const int* dstp = ei + E;

  hipFuncSetAttribute((const void*)gemm_t128<true>,
                      hipFuncAttributeMaxDynamicSharedMemorySize, 32768);
  hipFuncSetAttribute((const void*)gemm_p2<true>,
                      hipFuncAttributeMaxDynamicSharedMemorySize, 49152);

  // CSR build (by dst)
  hipMemsetAsync(counts, 0, (size_t)N * 4, stream);
  count_kernel<<<(E + 255) / 256, 256, 0, stream>>>(dstp, counts, E);
  scan_kernel<<<1, 1024, 0, stream>>>(counts, rowptr, cursor, N);
  fill_kernel<<<(E + 255) / 256, 256, 0, stream>>>(srcp, dstp, cursor, eidx, E);

  // prep: weight transposes, wa matvecs
  transpose_w<<<dim3(2048 / 32, 256 / 32), 256, 0, stream>>>(W1, Wt1, 256, 2048);
  transpose_w<<<dim3(2048 / 32, 2048 / 32), 256, 0, stream>>>(W2, Wt2, 2048, 2048);
  transpose_w<<<dim3(1024 / 32, 2048 / 32), 256, 0, stream>>>(W3, Wt3, 2048, 1024);
  matvec_wa<<<256, 256, 0, stream>>>(W1, a1s, a1d, wa1s, wa1d, 2048);
  matvec_wa<<<2048, 256, 0, stream>>>(W2, a2s, a2d, wa2s, wa2d, 2048);
  matvec_wa<<<2048, 256, 0, stream>>>(W3, a3s, a3d, wa3s, wa3d, 1024);

  dim3 blk(256);
  dim3 gblk(512);
  int mb128 = (N + 127) / 128;  // 79
  int mb256 = (N + 255) / 256;  // 40

  // layer 1: fused convert+al on x (F=256), agg, GEMM 256->2048 (t128)
  convert_al1<<<N, blk, 0, stream>>>(x, xb, wa1s, wa1d, als, ald);
  aggregate1<<<N, blk, 0, stream>>>(xb, als, ald, rowptr, eidx, hagg);
  gemm_t128<true><<<dim3(16, mb128), blk, 32768, stream>>>(hagg, (const ushort*)Wt1, b1, h, N, 256, 2048);

  // layer 2: al, agg, GEMM 2048->2048 (p2)
  compute_al8<<<N, blk, 0, stream>>>(h, wa2s, wa2d, als, ald);
  aggregate8<<<N, blk, 0, stream>>>(h, als, ald, rowptr, eidx, hagg);
  gemm_p2<true><<<dim3(16, mb256), gblk, 49152, stream>>>(hagg, (const ushort*)Wt2, b2, h, N, 2048, 2048);

  // layer 3: al, agg, GEMM 2048->1024 bf16 out (t128)
  compute_al8<<<N, blk, 0, stream>>>(h, wa3s, wa3d, als, ald);
  aggregate8<<<N, blk, 0, stream>>>(h, als, ald, rowptr, eidx, hagg);
  gemm_t128<true><<<dim3(8, mb128), blk, 32768, stream>>>(hagg, (const ushort*)Wt3, b3, h, N, 2048, 1024);

  // normalize from bf16 h -> f32 out
  normalize_bf16<<<N, blk, 0, stream>>>(h, (float*)d_out, 1024);
}